// Round 5
// baseline (4515.328 us; speedup 1.0000x reference)
//
#include <hip/hip_runtime.h>
#include <math.h>

#define DSZ 128
#define VOX (DSZ*DSZ*DSZ)  // 2,097,152 voxels

// ---------------------------------------------------------------------------
// Dense 3x3x3 SAME conv, 8 -> COUT, bias, optional relu. LDS-tiled input:
// block = 256 threads = output tile 128(W) x 2(H) x 1(D), halo tile
// 8ch x 3(z) x 4(y) x 130(x) = 49,920 B LDS. Weights read straight from
// global with wave-uniform indices -> scalar (s_load) path.
// ---------------------------------------------------------------------------
template<int COUT, bool RELU>
__global__ __launch_bounds__(256) void conv3x3t(const float* __restrict__ in,
                                                const float* __restrict__ wgt,
                                                const float* __restrict__ bias,
                                                float* __restrict__ out)
{
    __shared__ float tile[8 * 3 * 4 * 130];   // [ic][zz][yy][xx]
    const int tid = threadIdx.x;
    const int d0 = blockIdx.x >> 6;           // z plane
    const int h0 = (blockIdx.x & 63) << 1;    // first of 2 output rows

    const int x  = tid & 127;                 // w coordinate
    const int hi = tid >> 7;                  // 0/1: which output row

    #pragma unroll 4
    for (int it = 0; it < 48; ++it) {
        const int r  = it * 2 + hi;           // wave-uniform row id
        const int ic = r / 12;
        const int s  = r - ic * 12;
        const int zz = s >> 2;
        const int yy = s & 3;
        const int z = d0 + zz - 1;
        const int y = h0 + yy - 1;
        float v = 0.0f;
        if (((unsigned)z < DSZ) && ((unsigned)y < DSZ))
            v = in[(size_t)ic * VOX + (z << 14) + (y << 7) + x];
        tile[r * 130 + 1 + x] = v;
    }
    if (tid < 192) tile[(tid >> 1) * 130 + (tid & 1) * 129] = 0.0f;
    __syncthreads();

    float acc[COUT];
    #pragma unroll
    for (int oc = 0; oc < COUT; ++oc) acc[oc] = bias[oc];

    #pragma unroll
    for (int ic = 0; ic < 8; ++ic) {
        #pragma unroll
        for (int kd = 0; kd < 3; ++kd) {
            #pragma unroll
            for (int kh = 0; kh < 3; ++kh) {
                const float* tp = &tile[((ic * 3 + kd) * 4 + (hi + kh)) * 130 + x];
                const float t0 = tp[0], t1 = tp[1], t2 = tp[2];
                #pragma unroll
                for (int oc = 0; oc < COUT; ++oc) {
                    const float* wp = &wgt[(oc * 8 + ic) * 27 + kd * 9 + kh * 3];
                    acc[oc] = fmaf(t0, wp[0], acc[oc]);
                    acc[oc] = fmaf(t1, wp[1], acc[oc]);
                    acc[oc] = fmaf(t2, wp[2], acc[oc]);
                }
            }
        }
    }

    const int idx = (d0 << 14) + ((h0 + hi) << 7) + x;
    #pragma unroll
    for (int oc = 0; oc < COUT; ++oc) {
        float r = acc[oc];
        if (RELU) r = fmaxf(r, 0.0f);
        out[(size_t)oc * VOX + idx] = r;
    }
}

// ---------------------------------------------------------------------------
// 8 -> 27 conv + L1 normalize. Block = 256 thr = 4 waves, one (d,h) row of
// 128 voxels; wave w owns ocs [7w, 7w+7) (6 for w=3); thread handles voxels
// x=lane and x=lane+64. Input staged in LDS with halo: 8ch x 3z x 3y x 130x
// fp32 = 37,440 B; weights [tap][oc][ic] = 23,360 B; inner loop is pure
// ds_read + FMA (no boundary logic, no global address math).
// ---------------------------------------------------------------------------
template<typename WT>
__global__ __launch_bounds__(256) void conv8x27n(const float* __restrict__ in,
                                                 const float* __restrict__ wgt,
                                                 WT* __restrict__ out)
{
    __shared__ float tile[8 * 3 * 3 * 130];   // [ic][zz][yy][xx]
    __shared__ float lw[27 * 216 + 8];        // [tap][oc][ic] + pad
    __shared__ float red[2][64][5];           // [vslot][lane][wave]
    const int tid = threadIdx.x;
    const int h = blockIdx.x & 127;
    const int d = blockIdx.x >> 7;

    // stage weights
    for (int i = tid; i < 27 * 216; i += 256) {
        const int oc = i / 216, ic = (i / 27) & 7, tap = i % 27;
        lw[tap * 216 + oc * 8 + ic] = wgt[i];
    }
    if (tid < 8) lw[27 * 216 + tid] = 0.0f;

    // stage input tile: 72 rows (ic,zz,yy) x 130
    {
        const int xs = tid & 127;
        const int hs = tid >> 7;
        #pragma unroll 4
        for (int it = 0; it < 36; ++it) {
            const int r  = it * 2 + hs;
            const int ic = r / 9;
            const int s  = r - ic * 9;
            const int zz = s / 3;
            const int yy = s - zz * 3;
            const int z = d + zz - 1;
            const int y = h + yy - 1;
            float v = 0.0f;
            if (((unsigned)z < DSZ) && ((unsigned)y < DSZ))
                v = in[(size_t)ic * VOX + (z << 14) + (y << 7) + xs];
            tile[r * 130 + 1 + xs] = v;
        }
        if (tid < 144) tile[(tid >> 1) * 130 + (tid & 1) * 129] = 0.0f;
    }
    __syncthreads();

    const int lane = tid & 63;
    const int wv   = tid >> 6;
    const int noc  = (wv == 3) ? 6 : 7;
    const int oc0  = 7 * wv;

    const int idx0 = blockIdx.x * 128 + lane;
    const int idx1 = idx0 + 64;

    float acc[7][2];
    #pragma unroll
    for (int j = 0; j < 7; j++) { acc[j][0] = 0.0f; acc[j][1] = 0.0f; }

    #pragma unroll 1
    for (int kd = 0; kd < 3; kd++) {
        #pragma unroll
        for (int kh = 0; kh < 3; kh++) {
            #pragma unroll
            for (int kw = 0; kw < 3; kw++) {
                const int tap = kd * 9 + kh * 3 + kw;
                float v0[8], v1[8];
                #pragma unroll
                for (int ic = 0; ic < 8; ic++) {
                    const float* tp = &tile[((ic * 3 + kd) * 3 + kh) * 130 + kw];
                    v0[ic] = tp[lane];
                    v1[ic] = tp[lane + 64];
                }
                const float4* wp = (const float4*)&lw[tap * 216 + oc0 * 8];
                #pragma unroll
                for (int j = 0; j < 7; j++) {
                    const float4 wa = wp[2 * j];
                    const float4 wb = wp[2 * j + 1];
                    float a0 = acc[j][0], a1 = acc[j][1];
                    a0 = fmaf(wa.x, v0[0], a0); a1 = fmaf(wa.x, v1[0], a1);
                    a0 = fmaf(wa.y, v0[1], a0); a1 = fmaf(wa.y, v1[1], a1);
                    a0 = fmaf(wa.z, v0[2], a0); a1 = fmaf(wa.z, v1[2], a1);
                    a0 = fmaf(wa.w, v0[3], a0); a1 = fmaf(wa.w, v1[3], a1);
                    a0 = fmaf(wb.x, v0[4], a0); a1 = fmaf(wb.x, v1[4], a1);
                    a0 = fmaf(wb.y, v0[5], a0); a1 = fmaf(wb.y, v1[5], a1);
                    a0 = fmaf(wb.z, v0[6], a0); a1 = fmaf(wb.z, v1[6], a1);
                    a0 = fmaf(wb.w, v0[7], a0); a1 = fmaf(wb.w, v1[7], a1);
                    acc[j][0] = a0; acc[j][1] = a1;
                }
            }
        }
    }

    float s0 = 0.0f, s1 = 0.0f;
    for (int j = 0; j < noc; j++) { s0 += fabsf(acc[j][0]); s1 += fabsf(acc[j][1]); }
    red[0][lane][wv] = s0;
    red[1][lane][wv] = s1;
    __syncthreads();
    const float t0 = red[0][lane][0] + red[0][lane][1] + red[0][lane][2] + red[0][lane][3];
    const float t1 = red[1][lane][0] + red[1][lane][1] + red[1][lane][2] + red[1][lane][3];
    const float r0 = 1.0f / fmaxf(t0, 1e-12f);
    const float r1 = 1.0f / fmaxf(t1, 1e-12f);
    for (int j = 0; j < noc; j++) {
        out[(size_t)(oc0 + j) * VOX + idx0] = (WT)(acc[j][0] * r0);
        out[(size_t)(oc0 + j) * VOX + idx1] = (WT)(acc[j][1] * r1);
    }
}

// ---------------------------------------------------------------------------
// Adaptive stencil, LDS-tiled: block = 128(W) x 2(H) x 1(D) output tile,
// halo tile Cch x 3z x 4y x 130x fp32 (C=8: 49,920 B; C=1: 6,240 B).
// Inner loop: 27 per-voxel weights (registers) x C ds_read+FMA.
// ---------------------------------------------------------------------------
template<int C, bool TANH, typename WT>
__global__ __launch_bounds__(256) void aconv_t(const float* __restrict__ in,
                                               const WT* __restrict__ wb,
                                               float* __restrict__ out)
{
    __shared__ float tile[C * 3 * 4 * 130];
    const int tid = threadIdx.x;
    const int d0 = blockIdx.x >> 6;
    const int h0 = (blockIdx.x & 63) << 1;
    const int x  = tid & 127;
    const int hi = tid >> 7;

    #pragma unroll 4
    for (int it = 0; it < C * 6; ++it) {
        const int r  = it * 2 + hi;
        const int ic = r / 12;
        const int s  = r - ic * 12;
        const int zz = s >> 2;
        const int yy = s & 3;
        const int z = d0 + zz - 1;
        const int y = h0 + yy - 1;
        float v = 0.0f;
        if (((unsigned)z < DSZ) && ((unsigned)y < DSZ))
            v = in[(size_t)ic * VOX + (z << 14) + (y << 7) + x];
        tile[r * 130 + 1 + x] = v;
    }
    if (tid < C * 24) tile[(tid >> 1) * 130 + (tid & 1) * 129] = 0.0f;
    __syncthreads();

    const int idx = (d0 << 14) + ((h0 + hi) << 7) + x;

    float wv[27];
    #pragma unroll
    for (int t = 0; t < 27; t++) wv[t] = (float)wb[(size_t)t * VOX + idx];

    float acc[C];
    #pragma unroll
    for (int c = 0; c < C; c++) acc[c] = 0.0f;

    #pragma unroll
    for (int kd = 0; kd < 3; kd++) {
        #pragma unroll
        for (int kh = 0; kh < 3; kh++) {
            #pragma unroll
            for (int kw = 0; kw < 3; kw++) {
                const int tap = kd * 9 + kh * 3 + kw;
                #pragma unroll
                for (int c = 0; c < C; c++) {
                    const float t = tile[((c * 3 + kd) * 4 + (hi + kh)) * 130 + x + kw];
                    acc[c] = fmaf(t, wv[tap], acc[c]);
                }
            }
        }
    }

    #pragma unroll
    for (int c = 0; c < C; c++) {
        float r = TANH ? tanhf(acc[c]) : acc[c];
        out[(size_t)c * VOX + idx] = r;
    }
}

// ---------------------------------------------------------------------------
template<typename WT>
static void run_pipeline(const float* x, void* const* d_in, float* out,
                         float* R0, float* R1, WT* WB, hipStream_t stream)
{
    const float* ac1_w1 = (const float*)d_in[1];
    const float* ac1_b1 = (const float*)d_in[2];
    const float* ac1_w2 = (const float*)d_in[3];
    const float* ac2_w1 = (const float*)d_in[4];
    const float* ac2_b1 = (const float*)d_in[5];
    const float* ac2_w2 = (const float*)d_in[6];
    const float* ac3_w1 = (const float*)d_in[7];
    const float* ac3_b1 = (const float*)d_in[8];
    const float* ac3_w2 = (const float*)d_in[9];
    const float* mid_w  = (const float*)d_in[10];
    const float* mid_b  = (const float*)d_in[11];
    const float* out_w  = (const float*)d_in[12];
    const float* out_b  = (const float*)d_in[13];

    float* F1 = R0;
    float* F2 = R0 + VOX;

    const dim3 blk(256);
    const dim3 gridT(VOX / 256);   // conv3x3t / aconv_t: 256 voxels/block
    const dim3 gridN(VOX / 128);   // conv8x27n: 128 voxels/block

    // block 1
    conv3x3t<8, true ><<<gridT, blk, 0, stream>>>(x,  ac1_w1, ac1_b1, R0);
    conv8x27n<WT><<<gridN, blk, 0, stream>>>(R0, ac1_w2, WB);
    aconv_t<8, false, WT><<<gridT, blk, 0, stream>>>(x,  WB, R1);
    aconv_t<8, false, WT><<<gridT, blk, 0, stream>>>(R1, WB, R0);
    aconv_t<8, false, WT><<<gridT, blk, 0, stream>>>(R0, WB, R1);
    // mid conv
    conv3x3t<8, false><<<gridT, blk, 0, stream>>>(R1, mid_w, mid_b, R0);
    // block 2
    conv3x3t<8, true ><<<gridT, blk, 0, stream>>>(R0, ac2_w1, ac2_b1, R1);
    conv8x27n<WT><<<gridN, blk, 0, stream>>>(R1, ac2_w2, WB);
    aconv_t<8, false, WT><<<gridT, blk, 0, stream>>>(R0, WB, R1);
    aconv_t<8, false, WT><<<gridT, blk, 0, stream>>>(R1, WB, R0);
    aconv_t<8, false, WT><<<gridT, blk, 0, stream>>>(R0, WB, R1);   // mid2
    // block 3: weights from mid2 (R1)
    conv3x3t<8, true ><<<gridT, blk, 0, stream>>>(R1, ac3_w1, ac3_b1, R0);
    conv8x27n<WT><<<gridN, blk, 0, stream>>>(R0, ac3_w2, WB);
    conv3x3t<1, false><<<gridT, blk, 0, stream>>>(R1, out_w, out_b, F1);
    aconv_t<1, false, WT><<<gridT, blk, 0, stream>>>(F1, WB, F2);
    aconv_t<1, false, WT><<<gridT, blk, 0, stream>>>(F2, WB, F1);
    aconv_t<1, true,  WT><<<gridT, blk, 0, stream>>>(F1, WB, out);
}

extern "C" void kernel_launch(void* const* d_in, const int* in_sizes, int n_in,
                              void* d_out, int out_size, void* d_ws, size_t ws_size,
                              hipStream_t stream)
{
    const float* x = (const float*)d_in[0];
    float* out = (float*)d_out;

    char* ws = (char*)d_ws;
    const size_t CH8 = (size_t)8 * VOX * sizeof(float);          // 64 MB region
    float* R0 = (float*)(ws);
    float* R1 = (float*)(ws + CH8);
    void*  WBp = (void*)(ws + 2 * CH8);

    const size_t need_f32 = 2 * CH8 + (size_t)27 * VOX * sizeof(float);   // 344 MB

    if (ws_size >= need_f32) {
        run_pipeline<float>(x, d_in, out, R0, R1, (float*)WBp, stream);
    } else {
        run_pipeline<_Float16>(x, d_in, out, R0, R1, (_Float16*)WBp, stream);
    }
}

// Round 6
// 2909.479 us; speedup vs baseline: 1.5519x; 1.5519x over previous
//
#include <hip/hip_runtime.h>
#include <math.h>

#define DSZ 128
#define VOX (DSZ*DSZ*DSZ)  // 2,097,152 voxels

typedef _Float16 half8 __attribute__((ext_vector_type(8)));

// HP: fp16, channel-interleaved, x-padded hidden tensor.
// index(z,y,px) = ((z*128 + y)*130 + px)*8 halves, px = x+1, pad px=0,129.
#define HPROW 130
__device__ __forceinline__ size_t hp_idx(int z, int y, int px) {
    return ((size_t)((z << 7) + y) * HPROW + px) * 8;
}

// ---------------------------------------------------------------------------
// Zero the x-pad columns of HP (ws is re-poisoned before every timed call).
// ---------------------------------------------------------------------------
__global__ __launch_bounds__(256) void zero_pad_hp(_Float16* __restrict__ HP)
{
    const int t = blockIdx.x * 256 + threadIdx.x;   // 16384 (z,y) rows
    half8 zz = {};
    *(half8*)&HP[(size_t)t * HPROW * 8] = zz;           // px = 0
    *(half8*)&HP[(size_t)t * HPROW * 8 + 129 * 8] = zz; // px = 129
}

// ---------------------------------------------------------------------------
// Dense 3x3x3 conv 8->8 + bias + relu, planar fp32 in -> HP (fp16 interleaved).
// Block = 128(W) x 2(H) x 1(D) tile, input staged in LDS (proven R4 design).
// Weights via wave-uniform global reads (scalar path). XCD-swizzled blocks.
// ---------------------------------------------------------------------------
__global__ __launch_bounds__(256) void conv3x3h(const float* __restrict__ in,
                                                const float* __restrict__ wgt,
                                                const float* __restrict__ bias,
                                                _Float16* __restrict__ HP)
{
    __shared__ float tile[8 * 3 * 4 * 130];   // [ic][zz][yy][xx]
    const int tid = threadIdx.x;
    const int b = ((blockIdx.x & 7) << 10) | (blockIdx.x >> 3);  // 8192 blocks
    const int d0 = b >> 6;
    const int h0 = (b & 63) << 1;
    const int x  = tid & 127;
    const int hi = tid >> 7;

    #pragma unroll 4
    for (int it = 0; it < 48; ++it) {
        const int r  = it * 2 + hi;
        const int ic = r / 12;
        const int s  = r - ic * 12;
        const int zz = s >> 2;
        const int yy = s & 3;
        const int z = d0 + zz - 1;
        const int y = h0 + yy - 1;
        float v = 0.0f;
        if (((unsigned)z < DSZ) && ((unsigned)y < DSZ))
            v = in[(size_t)ic * VOX + (z << 14) + (y << 7) + x];
        tile[r * 130 + 1 + x] = v;
    }
    if (tid < 192) tile[(tid >> 1) * 130 + (tid & 1) * 129] = 0.0f;
    __syncthreads();

    float acc[8];
    #pragma unroll
    for (int oc = 0; oc < 8; ++oc) acc[oc] = bias[oc];

    #pragma unroll
    for (int ic = 0; ic < 8; ++ic) {
        #pragma unroll
        for (int kd = 0; kd < 3; ++kd) {
            #pragma unroll
            for (int kh = 0; kh < 3; ++kh) {
                const float* tp = &tile[((ic * 3 + kd) * 4 + (hi + kh)) * 130 + x];
                const float t0 = tp[0], t1 = tp[1], t2 = tp[2];
                #pragma unroll
                for (int oc = 0; oc < 8; ++oc) {
                    const float* wp = &wgt[(oc * 8 + ic) * 27 + kd * 9 + kh * 3];
                    acc[oc] = fmaf(t0, wp[0], acc[oc]);
                    acc[oc] = fmaf(t1, wp[1], acc[oc]);
                    acc[oc] = fmaf(t2, wp[2], acc[oc]);
                }
            }
        }
    }

    half8 hv;
    #pragma unroll
    for (int oc = 0; oc < 8; ++oc) hv[oc] = (_Float16)fmaxf(acc[oc], 0.0f);
    *(half8*)&HP[hp_idx(d0, h0 + hi, x + 1)] = hv;
}

// ---------------------------------------------------------------------------
// Dense 3x3x3 conv 8->COUT planar fp32 (mid / out convs). R4 design + swizzle.
// ---------------------------------------------------------------------------
template<int COUT, bool RELU>
__global__ __launch_bounds__(256) void conv3x3t(const float* __restrict__ in,
                                                const float* __restrict__ wgt,
                                                const float* __restrict__ bias,
                                                float* __restrict__ out)
{
    __shared__ float tile[8 * 3 * 4 * 130];
    const int tid = threadIdx.x;
    const int b = ((blockIdx.x & 7) << 10) | (blockIdx.x >> 3);
    const int d0 = b >> 6;
    const int h0 = (b & 63) << 1;
    const int x  = tid & 127;
    const int hi = tid >> 7;

    #pragma unroll 4
    for (int it = 0; it < 48; ++it) {
        const int r  = it * 2 + hi;
        const int ic = r / 12;
        const int s  = r - ic * 12;
        const int zz = s >> 2;
        const int yy = s & 3;
        const int z = d0 + zz - 1;
        const int y = h0 + yy - 1;
        float v = 0.0f;
        if (((unsigned)z < DSZ) && ((unsigned)y < DSZ))
            v = in[(size_t)ic * VOX + (z << 14) + (y << 7) + x];
        tile[r * 130 + 1 + x] = v;
    }
    if (tid < 192) tile[(tid >> 1) * 130 + (tid & 1) * 129] = 0.0f;
    __syncthreads();

    float acc[COUT];
    #pragma unroll
    for (int oc = 0; oc < COUT; ++oc) acc[oc] = bias[oc];

    #pragma unroll
    for (int ic = 0; ic < 8; ++ic) {
        #pragma unroll
        for (int kd = 0; kd < 3; ++kd) {
            #pragma unroll
            for (int kh = 0; kh < 3; ++kh) {
                const float* tp = &tile[((ic * 3 + kd) * 4 + (hi + kh)) * 130 + x];
                const float t0 = tp[0], t1 = tp[1], t2 = tp[2];
                #pragma unroll
                for (int oc = 0; oc < COUT; ++oc) {
                    const float* wp = &wgt[(oc * 8 + ic) * 27 + kd * 9 + kh * 3];
                    acc[oc] = fmaf(t0, wp[0], acc[oc]);
                    acc[oc] = fmaf(t1, wp[1], acc[oc]);
                    acc[oc] = fmaf(t2, wp[2], acc[oc]);
                }
            }
        }
    }

    const int idx = (d0 << 14) + ((h0 + hi) << 7) + x;
    #pragma unroll
    for (int oc = 0; oc < COUT; ++oc) {
        float r = acc[oc];
        if (RELU) r = fmaxf(r, 0.0f);
        out[(size_t)oc * VOX + idx] = r;
    }
}

// ---------------------------------------------------------------------------
// 8 -> 27 conv + L1 normalize from HP (fp16 interleaved x-padded).
// Block = 4 waves over one (d,h) row of 128 voxels; wave w owns ocs
// [7w,7w+7) (6 for w=3); thread handles x=lane and x=lane+64.
// Per tap: ONE dwordx4 load per voxel (pure immediate offsets), z/y boundary
// = block-uniform scalar branch. Weights in LDS [tap][oc][ic].
// ---------------------------------------------------------------------------
__global__ __launch_bounds__(256) void conv8x27n(const _Float16* __restrict__ HP,
                                                 const float* __restrict__ wgt,
                                                 _Float16* __restrict__ out)
{
    __shared__ float lw[27 * 216 + 8];
    __shared__ float red[2][64][5];
    const int tid = threadIdx.x;
    const int b = ((blockIdx.x & 7) << 11) | (blockIdx.x >> 3);  // 16384 blocks
    const int h = b & 127;
    const int d = b >> 7;

    for (int i = tid; i < 27 * 216; i += 256) {
        const int oc = i / 216, ic = (i / 27) & 7, tap = i % 27;
        lw[tap * 216 + oc * 8 + ic] = wgt[i];
    }
    if (tid < 8) lw[27 * 216 + tid] = 0.0f;
    __syncthreads();

    const int lane = tid & 63;
    const int wv   = tid >> 6;
    const int noc  = (wv == 3) ? 6 : 7;
    const int oc0  = 7 * wv;

    const int idx0 = b * 128 + lane;
    const int idx1 = idx0 + 64;

    float acc[7][2];
    #pragma unroll
    for (int j = 0; j < 7; j++) { acc[j][0] = 0.0f; acc[j][1] = 0.0f; }

    #pragma unroll
    for (int kd = 0; kd < 3; kd++) {
        const int z = d + kd - 1;
        if ((unsigned)z >= DSZ) continue;          // block-uniform scalar branch
        #pragma unroll
        for (int kh = 0; kh < 3; kh++) {
            const int y = h + kh - 1;
            if ((unsigned)y >= DSZ) continue;      // block-uniform scalar branch
            // px for voxel0 at kw: lane + kw (kw-1 tap offset + 1 pad shift)
            const _Float16* rp = HP + hp_idx(z, y, lane);
            #pragma unroll
            for (int kw = 0; kw < 3; kw++) {
                const int tap = kd * 9 + kh * 3 + kw;
                const half8 hv0 = *(const half8*)(rp + kw * 8);        // voxel0
                const half8 hv1 = *(const half8*)(rp + kw * 8 + 512);  // voxel1 (+64 vox)
                float v0[8], v1[8];
                #pragma unroll
                for (int ic = 0; ic < 8; ic++) {
                    v0[ic] = (float)hv0[ic];
                    v1[ic] = (float)hv1[ic];
                }
                const float4* wp = (const float4*)&lw[tap * 216 + oc0 * 8];
                #pragma unroll
                for (int j = 0; j < 7; j++) {
                    const float4 wa = wp[2 * j];
                    const float4 wb = wp[2 * j + 1];
                    float a0 = acc[j][0], a1 = acc[j][1];
                    a0 = fmaf(wa.x, v0[0], a0); a1 = fmaf(wa.x, v1[0], a1);
                    a0 = fmaf(wa.y, v0[1], a0); a1 = fmaf(wa.y, v1[1], a1);
                    a0 = fmaf(wa.z, v0[2], a0); a1 = fmaf(wa.z, v1[2], a1);
                    a0 = fmaf(wa.w, v0[3], a0); a1 = fmaf(wa.w, v1[3], a1);
                    a0 = fmaf(wb.x, v0[4], a0); a1 = fmaf(wb.x, v1[4], a1);
                    a0 = fmaf(wb.y, v0[5], a0); a1 = fmaf(wb.y, v1[5], a1);
                    a0 = fmaf(wb.z, v0[6], a0); a1 = fmaf(wb.z, v1[6], a1);
                    a0 = fmaf(wb.w, v0[7], a0); a1 = fmaf(wb.w, v1[7], a1);
                    acc[j][0] = a0; acc[j][1] = a1;
                }
            }
        }
    }

    float s0 = 0.0f, s1 = 0.0f;
    for (int j = 0; j < noc; j++) { s0 += fabsf(acc[j][0]); s1 += fabsf(acc[j][1]); }
    red[0][lane][wv] = s0;
    red[1][lane][wv] = s1;
    __syncthreads();
    const float t0 = red[0][lane][0] + red[0][lane][1] + red[0][lane][2] + red[0][lane][3];
    const float t1 = red[1][lane][0] + red[1][lane][1] + red[1][lane][2] + red[1][lane][3];
    const float r0 = 1.0f / fmaxf(t0, 1e-12f);
    const float r1 = 1.0f / fmaxf(t1, 1e-12f);
    for (int j = 0; j < noc; j++) {
        out[(size_t)(oc0 + j) * VOX + idx0] = (_Float16)(acc[j][0] * r0);
        out[(size_t)(oc0 + j) * VOX + idx1] = (_Float16)(acc[j][1] * r1);
    }
}

// ---------------------------------------------------------------------------
// Adaptive stencil (R2-winning design: no LDS, 32 VGPR) + XCD swizzle.
// ---------------------------------------------------------------------------
template<int C, bool TANH>
__global__ __launch_bounds__(256) void aconv(const float* __restrict__ in,
                                             const _Float16* __restrict__ wb,
                                             float* __restrict__ out)
{
    const int b = ((blockIdx.x & 7) << 10) | (blockIdx.x >> 3);  // 8192 blocks
    const int idx = b * 256 + threadIdx.x;
    const int w = idx & (DSZ - 1);
    const int h = (idx >> 7) & (DSZ - 1);
    const int d = idx >> 14;

    float wv[27];
    #pragma unroll
    for (int t = 0; t < 27; t++) wv[t] = (float)wb[(size_t)t * VOX + idx];

    float acc[C];
    #pragma unroll
    for (int c = 0; c < C; c++) acc[c] = 0.0f;

    #pragma unroll 1
    for (int kd = 0; kd < 3; kd++) {
        const int z = d + kd - 1;
        const bool okz = ((unsigned)z < DSZ);
        #pragma unroll
        for (int kh = 0; kh < 3; kh++) {
            const int y = h + kh - 1;
            const bool oky = okz && ((unsigned)y < DSZ);
            #pragma unroll
            for (int kw = 0; kw < 3; kw++) {
                const int xx = w + kw - 1;
                const bool ok = oky && ((unsigned)xx < DSZ);
                const int off = ok ? ((z * DSZ + y) * DSZ + xx) : idx;
                const int tap = kd * 9 + kh * 3 + kw;
                #pragma unroll
                for (int c = 0; c < C; c++) {
                    float t = in[(size_t)c * VOX + off];
                    acc[c] = fmaf(ok ? t : 0.0f, wv[tap], acc[c]);
                }
            }
        }
    }

    #pragma unroll
    for (int c = 0; c < C; c++) {
        float r = TANH ? tanhf(acc[c]) : acc[c];
        out[(size_t)c * VOX + idx] = r;
    }
}

// ---------------------------------------------------------------------------
// ws layout (236 MB): R0 (64 MB) | R1 (64 MB) | WB (fp16, 108 MB).
// HP (32.5 MB fp16) lives in whichever of R0/R1 is dead; F1/F2 at R0+40/48 MB.
// ---------------------------------------------------------------------------
extern "C" void kernel_launch(void* const* d_in, const int* in_sizes, int n_in,
                              void* d_out, int out_size, void* d_ws, size_t ws_size,
                              hipStream_t stream)
{
    const float* x      = (const float*)d_in[0];
    const float* ac1_w1 = (const float*)d_in[1];
    const float* ac1_b1 = (const float*)d_in[2];
    const float* ac1_w2 = (const float*)d_in[3];
    const float* ac2_w1 = (const float*)d_in[4];
    const float* ac2_b1 = (const float*)d_in[5];
    const float* ac2_w2 = (const float*)d_in[6];
    const float* ac3_w1 = (const float*)d_in[7];
    const float* ac3_b1 = (const float*)d_in[8];
    const float* ac3_w2 = (const float*)d_in[9];
    const float* mid_w  = (const float*)d_in[10];
    const float* mid_b  = (const float*)d_in[11];
    const float* out_w  = (const float*)d_in[12];
    const float* out_b  = (const float*)d_in[13];
    float* out = (float*)d_out;

    char* ws = (char*)d_ws;
    const size_t MB = 1024 * 1024;
    float*     R0  = (float*)(ws);
    float*     R1  = (float*)(ws + 64 * MB);
    _Float16*  WB  = (_Float16*)(ws + 128 * MB);
    _Float16*  HPa = (_Float16*)R0;                 // HP when R0 is dead
    _Float16*  HPb = (_Float16*)R1;                 // HP when R1 is dead
    float*     F1  = (float*)(ws + 40 * MB);
    float*     F2  = (float*)(ws + 48 * MB);

    const dim3 blk(256);
    const dim3 gridT(VOX / 256);   // conv3x3h/t, aconv: 256 voxels/block
    const dim3 gridN(VOX / 128);   // conv8x27n: 128 voxels/block
    const dim3 gridP(64);          // zero_pad_hp

    // ---- block 1 (input x; HP in R0) ----
    zero_pad_hp<<<gridP, blk, 0, stream>>>(HPa);
    conv3x3h<<<gridT, blk, 0, stream>>>(x, ac1_w1, ac1_b1, HPa);
    conv8x27n<<<gridN, blk, 0, stream>>>(HPa, ac1_w2, WB);
    aconv<8, false><<<gridT, blk, 0, stream>>>(x,  WB, R1);
    aconv<8, false><<<gridT, blk, 0, stream>>>(R1, WB, R0);
    aconv<8, false><<<gridT, blk, 0, stream>>>(R0, WB, R1);
    // ---- mid conv ----
    conv3x3t<8, false><<<gridT, blk, 0, stream>>>(R1, mid_w, mid_b, R0);   // M = R0
    // ---- block 2 (on M; HP in R1) ----
    zero_pad_hp<<<gridP, blk, 0, stream>>>(HPb);
    conv3x3h<<<gridT, blk, 0, stream>>>(R0, ac2_w1, ac2_b1, HPb);
    conv8x27n<<<gridN, blk, 0, stream>>>(HPb, ac2_w2, WB);
    aconv<8, false><<<gridT, blk, 0, stream>>>(R0, WB, R1);
    aconv<8, false><<<gridT, blk, 0, stream>>>(R1, WB, R0);
    aconv<8, false><<<gridT, blk, 0, stream>>>(R0, WB, R1);   // mid2 = R1
    // ---- block 3 (weights from mid2 = R1; HP in R0) ----
    zero_pad_hp<<<gridP, blk, 0, stream>>>(HPa);
    conv3x3h<<<gridT, blk, 0, stream>>>(R1, ac3_w1, ac3_b1, HPa);
    conv8x27n<<<gridN, blk, 0, stream>>>(HPa, ac3_w2, WB);
    conv3x3t<1, false><<<gridT, blk, 0, stream>>>(R1, out_w, out_b, F1);
    aconv<1, false><<<gridT, blk, 0, stream>>>(F1, WB, F2);
    aconv<1, false><<<gridT, blk, 0, stream>>>(F2, WB, F1);
    aconv<1, true ><<<gridT, blk, 0, stream>>>(F1, WB, out);
}

// Round 7
// 2146.975 us; speedup vs baseline: 2.1031x; 1.3552x over previous
//
#include <hip/hip_runtime.h>
#include <math.h>

#define DSZ 128
#define VOX (DSZ*DSZ*DSZ)  // 2,097,152 voxels

typedef _Float16 half8 __attribute__((ext_vector_type(8)));
typedef float float4v __attribute__((ext_vector_type(4)));

// HP: fp16, channel-interleaved, x-padded hidden tensor.
// index(z,y,px) = ((z*128 + y)*130 + px)*8 halves, px = x+1, pad px=0,129 (zeroed).
#define HPROW 130
__device__ __forceinline__ size_t hp_idx(int z, int y, int px) {
    return ((size_t)((z << 7) + y) * HPROW + px) * 8;
}

// ---------------------------------------------------------------------------
__global__ __launch_bounds__(256) void zero_pad_hp(_Float16* __restrict__ HP)
{
    const int t = blockIdx.x * 256 + threadIdx.x;   // 16384 (z,y) rows
    half8 zz = {};
    *(half8*)&HP[(size_t)t * HPROW * 8] = zz;           // px = 0
    *(half8*)&HP[(size_t)t * HPROW * 8 + 129 * 8] = zz; // px = 129
}

// ---------------------------------------------------------------------------
// Dense 3x3x3 conv 8->8 + bias + relu, planar fp32 in -> HP (fp16 interleaved).
// ---------------------------------------------------------------------------
__global__ __launch_bounds__(256) void conv3x3h(const float* __restrict__ in,
                                                const float* __restrict__ wgt,
                                                const float* __restrict__ bias,
                                                _Float16* __restrict__ HP)
{
    __shared__ float tile[8 * 3 * 4 * 130];   // [ic][zz][yy][xx]
    const int tid = threadIdx.x;
    const int b = ((blockIdx.x & 7) << 10) | (blockIdx.x >> 3);  // 8192 blocks
    const int d0 = b >> 6;
    const int h0 = (b & 63) << 1;
    const int x  = tid & 127;
    const int hi = tid >> 7;

    #pragma unroll 4
    for (int it = 0; it < 48; ++it) {
        const int r  = it * 2 + hi;
        const int ic = r / 12;
        const int s  = r - ic * 12;
        const int zz = s >> 2;
        const int yy = s & 3;
        const int z = d0 + zz - 1;
        const int y = h0 + yy - 1;
        float v = 0.0f;
        if (((unsigned)z < DSZ) && ((unsigned)y < DSZ))
            v = in[(size_t)ic * VOX + (z << 14) + (y << 7) + x];
        tile[r * 130 + 1 + x] = v;
    }
    if (tid < 192) tile[(tid >> 1) * 130 + (tid & 1) * 129] = 0.0f;
    __syncthreads();

    float acc[8];
    #pragma unroll
    for (int oc = 0; oc < 8; ++oc) acc[oc] = bias[oc];

    #pragma unroll
    for (int ic = 0; ic < 8; ++ic) {
        #pragma unroll
        for (int kd = 0; kd < 3; ++kd) {
            #pragma unroll
            for (int kh = 0; kh < 3; ++kh) {
                const float* tp = &tile[((ic * 3 + kd) * 4 + (hi + kh)) * 130 + x];
                const float t0 = tp[0], t1 = tp[1], t2 = tp[2];
                #pragma unroll
                for (int oc = 0; oc < 8; ++oc) {
                    const float* wp = &wgt[(oc * 8 + ic) * 27 + kd * 9 + kh * 3];
                    acc[oc] = fmaf(t0, wp[0], acc[oc]);
                    acc[oc] = fmaf(t1, wp[1], acc[oc]);
                    acc[oc] = fmaf(t2, wp[2], acc[oc]);
                }
            }
        }
    }

    half8 hv;
    #pragma unroll
    for (int oc = 0; oc < 8; ++oc) hv[oc] = (_Float16)fmaxf(acc[oc], 0.0f);
    *(half8*)&HP[hp_idx(d0, h0 + hi, x + 1)] = hv;
}

// ---------------------------------------------------------------------------
// Dense 3x3x3 conv 8->COUT planar fp32 (mid / out convs).
// ---------------------------------------------------------------------------
template<int COUT, bool RELU>
__global__ __launch_bounds__(256) void conv3x3t(const float* __restrict__ in,
                                                const float* __restrict__ wgt,
                                                const float* __restrict__ bias,
                                                float* __restrict__ out)
{
    __shared__ float tile[8 * 3 * 4 * 130];
    const int tid = threadIdx.x;
    const int b = ((blockIdx.x & 7) << 10) | (blockIdx.x >> 3);
    const int d0 = b >> 6;
    const int h0 = (b & 63) << 1;
    const int x  = tid & 127;
    const int hi = tid >> 7;

    #pragma unroll 4
    for (int it = 0; it < 48; ++it) {
        const int r  = it * 2 + hi;
        const int ic = r / 12;
        const int s  = r - ic * 12;
        const int zz = s >> 2;
        const int yy = s & 3;
        const int z = d0 + zz - 1;
        const int y = h0 + yy - 1;
        float v = 0.0f;
        if (((unsigned)z < DSZ) && ((unsigned)y < DSZ))
            v = in[(size_t)ic * VOX + (z << 14) + (y << 7) + x];
        tile[r * 130 + 1 + x] = v;
    }
    if (tid < 192) tile[(tid >> 1) * 130 + (tid & 1) * 129] = 0.0f;
    __syncthreads();

    float acc[COUT];
    #pragma unroll
    for (int oc = 0; oc < COUT; ++oc) acc[oc] = bias[oc];

    #pragma unroll
    for (int ic = 0; ic < 8; ++ic) {
        #pragma unroll
        for (int kd = 0; kd < 3; ++kd) {
            #pragma unroll
            for (int kh = 0; kh < 3; ++kh) {
                const float* tp = &tile[((ic * 3 + kd) * 4 + (hi + kh)) * 130 + x];
                const float t0 = tp[0], t1 = tp[1], t2 = tp[2];
                #pragma unroll
                for (int oc = 0; oc < COUT; ++oc) {
                    const float* wp = &wgt[(oc * 8 + ic) * 27 + kd * 9 + kh * 3];
                    acc[oc] = fmaf(t0, wp[0], acc[oc]);
                    acc[oc] = fmaf(t1, wp[1], acc[oc]);
                    acc[oc] = fmaf(t2, wp[2], acc[oc]);
                }
            }
        }
    }

    const int idx = (d0 << 14) + ((h0 + hi) << 7) + x;
    #pragma unroll
    for (int oc = 0; oc < COUT; ++oc) {
        float r = acc[oc];
        if (RELU) r = fmaxf(r, 0.0f);
        out[(size_t)oc * VOX + idx] = r;
    }
}

// ---------------------------------------------------------------------------
// 8 -> 27 conv + L1 normalize via MFMA (f16 in, f32 acc).
// GEMM view: D[27, VOX] = W[27, 216] x X[216, VOX], K = tap*8 + ic.
// Block = 256 thr = 4 waves over one (d,h) row of 128 voxels; wave handles
// 2 n-tiles of 16 voxels. M: 2 tiles (27 -> pad 32, Wr zero-padded).
// K: 7 chunks of 32 (tap 27 pad -> zero weights).
// B-frag: lane holds half8 = HP[z+dz, y+dy, x(n)+dx] -> ONE dwordx4/lane/chunk.
// z/y-OOB taps: block-uniform per lane -> zero A-frag lanes; x-OOB via HP pad.
// L1 denom: per-lane |acc| partials + shfl_xor(16), shfl_xor(32) over quads.
// ---------------------------------------------------------------------------
__global__ __launch_bounds__(256) void conv8x27n_mfma(const _Float16* __restrict__ HP,
                                                      const float* __restrict__ wgt,
                                                      _Float16* __restrict__ out)
{
    __shared__ _Float16 Wr[32 * 28 * 8];   // [oc][tap][ic] fp16, zero-padded; 14,336 B
    const int tid = threadIdx.x;

    for (int i = tid; i < 32 * 28; i += 256) ((half8*)Wr)[i] = half8{};
    __syncthreads();
    for (int i = tid; i < 27 * 216; i += 256) {
        const int oc = i / 216;
        const int rem = i - oc * 216;
        const int ic = rem / 27;
        const int tap = rem - ic * 27;
        Wr[(oc * 28 + tap) * 8 + ic] = (_Float16)wgt[i];
    }
    __syncthreads();

    const int b = ((blockIdx.x & 7) << 11) | (blockIdx.x >> 3);  // 16384 blocks
    const int h = b & 127;
    const int d = b >> 7;
    const int lane = tid & 63;
    const int wv   = tid >> 6;
    const int col  = lane & 15;   // n within tile
    const int q    = lane >> 4;   // 0..3

    // ---- A-fragments: af[mtile][chunk], lane holds W[oc = t*16+col][tap = c*4+q][ic=0..7]
    half8 af[2][7];
    #pragma unroll
    for (int t = 0; t < 2; ++t)
        #pragma unroll
        for (int c = 0; c < 7; ++c)
            af[t][c] = *(const half8*)&Wr[((t * 16 + col) * 28 + (c * 4 + q)) * 8];

    // ---- per-chunk source row offset (halves) for this lane's tap + validity
    int rowoff[7];
    #pragma unroll
    for (int c = 0; c < 7; ++c) {
        int tap = c * 4 + q; if (tap > 26) tap = 26;     // pad tap: A is zero anyway
        const int dz = tap / 9 - 1;
        const int dy = (tap / 3) % 3 - 1;
        const int dx = tap - (tap / 3) * 3 - 1;
        const int z = d + dz, y = h + dy;
        const bool ok = ((unsigned)z < DSZ) && ((unsigned)y < DSZ);
        const int zc = min(max(z, 0), DSZ - 1);
        const int yc = min(max(y, 0), DSZ - 1);
        rowoff[c] = (((zc << 7) + yc) * HPROW + (dx + 1)) * 8;
        if (!ok) { af[0][c] = half8{}; af[1][c] = half8{}; }  // zero weights -> zero contrib
    }

    // ---- 2 n-tiles per wave
    #pragma unroll
    for (int t2 = 0; t2 < 2; ++t2) {
        const int xb = wv * 32 + t2 * 16;
        float4v acc0 = {0.0f, 0.0f, 0.0f, 0.0f};
        float4v acc1 = {0.0f, 0.0f, 0.0f, 0.0f};
        const int xoff = (xb + col) * 8;

        #pragma unroll
        for (int c = 0; c < 7; ++c) {
            const half8 bv = *(const half8*)(HP + rowoff[c] + xoff);  // clamped rows: always valid mem
            acc0 = __builtin_amdgcn_mfma_f32_16x16x32_f16(af[0][c], bv, acc0, 0, 0, 0);
            acc1 = __builtin_amdgcn_mfma_f32_16x16x32_f16(af[1][c], bv, acc1, 0, 0, 0);
        }

        // ---- L1 normalize over 27 ocs for this voxel column
        float s = 0.0f;
        #pragma unroll
        for (int r = 0; r < 4; ++r) {
            s += fabsf(acc0[r]);
            if (16 + q * 4 + r < 27) s += fabsf(acc1[r]);
        }
        s += __shfl_xor(s, 16);
        s += __shfl_xor(s, 32);
        const float rcp = 1.0f / fmaxf(s, 1e-12f);

        const int vox = (d << 14) + (h << 7) + xb + col;
        #pragma unroll
        for (int r = 0; r < 4; ++r) {
            out[(size_t)(q * 4 + r) * VOX + vox] = (_Float16)(acc0[r] * rcp);
            const int oc1 = 16 + q * 4 + r;
            if (oc1 < 27)
                out[(size_t)oc1 * VOX + vox] = (_Float16)(acc1[r] * rcp);
        }
    }
}

// ---------------------------------------------------------------------------
// Adaptive stencil (R2-winning design: no LDS, 32 VGPR) + XCD swizzle.
// ---------------------------------------------------------------------------
template<int C, bool TANH>
__global__ __launch_bounds__(256) void aconv(const float* __restrict__ in,
                                             const _Float16* __restrict__ wb,
                                             float* __restrict__ out)
{
    const int b = ((blockIdx.x & 7) << 10) | (blockIdx.x >> 3);  // 8192 blocks
    const int idx = b * 256 + threadIdx.x;
    const int w = idx & (DSZ - 1);
    const int h = (idx >> 7) & (DSZ - 1);
    const int d = idx >> 14;

    float wv[27];
    #pragma unroll
    for (int t = 0; t < 27; t++) wv[t] = (float)wb[(size_t)t * VOX + idx];

    float acc[C];
    #pragma unroll
    for (int c = 0; c < C; c++) acc[c] = 0.0f;

    #pragma unroll 1
    for (int kd = 0; kd < 3; kd++) {
        const int z = d + kd - 1;
        const bool okz = ((unsigned)z < DSZ);
        #pragma unroll
        for (int kh = 0; kh < 3; kh++) {
            const int y = h + kh - 1;
            const bool oky = okz && ((unsigned)y < DSZ);
            #pragma unroll
            for (int kw = 0; kw < 3; kw++) {
                const int xx = w + kw - 1;
                const bool ok = oky && ((unsigned)xx < DSZ);
                const int off = ok ? ((z * DSZ + y) * DSZ + xx) : idx;
                const int tap = kd * 9 + kh * 3 + kw;
                #pragma unroll
                for (int c = 0; c < C; c++) {
                    float t = in[(size_t)c * VOX + off];
                    acc[c] = fmaf(ok ? t : 0.0f, wv[tap], acc[c]);
                }
            }
        }
    }

    #pragma unroll
    for (int c = 0; c < C; c++) {
        float r = TANH ? tanhf(acc[c]) : acc[c];
        out[(size_t)c * VOX + idx] = r;
    }
}

// ---------------------------------------------------------------------------
// ws layout (236 MB): R0 (64 MB) | R1 (64 MB) | WB (fp16, 108 MB).
// HP (32.5 MB fp16) lives in whichever of R0/R1 is dead; F1/F2 at R0+40/48 MB.
// ---------------------------------------------------------------------------
extern "C" void kernel_launch(void* const* d_in, const int* in_sizes, int n_in,
                              void* d_out, int out_size, void* d_ws, size_t ws_size,
                              hipStream_t stream)
{
    const float* x      = (const float*)d_in[0];
    const float* ac1_w1 = (const float*)d_in[1];
    const float* ac1_b1 = (const float*)d_in[2];
    const float* ac1_w2 = (const float*)d_in[3];
    const float* ac2_w1 = (const float*)d_in[4];
    const float* ac2_b1 = (const float*)d_in[5];
    const float* ac2_w2 = (const float*)d_in[6];
    const float* ac3_w1 = (const float*)d_in[7];
    const float* ac3_b1 = (const float*)d_in[8];
    const float* ac3_w2 = (const float*)d_in[9];
    const float* mid_w  = (const float*)d_in[10];
    const float* mid_b  = (const float*)d_in[11];
    const float* out_w  = (const float*)d_in[12];
    const float* out_b  = (const float*)d_in[13];
    float* out = (float*)d_out;

    char* ws = (char*)d_ws;
    const size_t MB = 1024 * 1024;
    float*     R0  = (float*)(ws);
    float*     R1  = (float*)(ws + 64 * MB);
    _Float16*  WB  = (_Float16*)(ws + 128 * MB);
    _Float16*  HPa = (_Float16*)R0;                 // HP when R0 is dead
    _Float16*  HPb = (_Float16*)R1;                 // HP when R1 is dead
    float*     F1  = (float*)(ws + 40 * MB);
    float*     F2  = (float*)(ws + 48 * MB);

    const dim3 blk(256);
    const dim3 gridT(VOX / 256);   // conv3x3h/t, aconv: 256 voxels/block
    const dim3 gridN(VOX / 128);   // conv8x27n_mfma: 128 voxels/block
    const dim3 gridP(64);          // zero_pad_hp

    // ---- block 1 (input x; HP in R0) ----
    zero_pad_hp<<<gridP, blk, 0, stream>>>(HPa);
    conv3x3h<<<gridT, blk, 0, stream>>>(x, ac1_w1, ac1_b1, HPa);
    conv8x27n_mfma<<<gridN, blk, 0, stream>>>(HPa, ac1_w2, WB);
    aconv<8, false><<<gridT, blk, 0, stream>>>(x,  WB, R1);
    aconv<8, false><<<gridT, blk, 0, stream>>>(R1, WB, R0);
    aconv<8, false><<<gridT, blk, 0, stream>>>(R0, WB, R1);
    // ---- mid conv ----
    conv3x3t<8, false><<<gridT, blk, 0, stream>>>(R1, mid_w, mid_b, R0);   // M = R0
    // ---- block 2 (on M; HP in R1) ----
    zero_pad_hp<<<gridP, blk, 0, stream>>>(HPb);
    conv3x3h<<<gridT, blk, 0, stream>>>(R0, ac2_w1, ac2_b1, HPb);
    conv8x27n_mfma<<<gridN, blk, 0, stream>>>(HPb, ac2_w2, WB);
    aconv<8, false><<<gridT, blk, 0, stream>>>(R0, WB, R1);
    aconv<8, false><<<gridT, blk, 0, stream>>>(R1, WB, R0);
    aconv<8, false><<<gridT, blk, 0, stream>>>(R0, WB, R1);   // mid2 = R1
    // ---- block 3 (weights from mid2 = R1; HP in R0) ----
    zero_pad_hp<<<gridP, blk, 0, stream>>>(HPa);
    conv3x3h<<<gridT, blk, 0, stream>>>(R1, ac3_w1, ac3_b1, HPa);
    conv8x27n_mfma<<<gridN, blk, 0, stream>>>(HPa, ac3_w2, WB);
    conv3x3t<1, false><<<gridT, blk, 0, stream>>>(R1, out_w, out_b, F1);
    aconv<1, false><<<gridT, blk, 0, stream>>>(F1, WB, F2);
    aconv<1, false><<<gridT, blk, 0, stream>>>(F2, WB, F1);
    aconv<1, true ><<<gridT, blk, 0, stream>>>(F1, WB, out);
}

// Round 8
// 1689.484 us; speedup vs baseline: 2.6726x; 1.2708x over previous
//
#include <hip/hip_runtime.h>
#include <math.h>

#define DSZ 128
#define VOX (DSZ*DSZ*DSZ)  // 2,097,152 voxels

typedef _Float16 half8 __attribute__((ext_vector_type(8)));
typedef _Float16 half4 __attribute__((ext_vector_type(4)));
typedef float float4v __attribute__((ext_vector_type(4)));

// HP format: fp16, channel-interleaved [vox][8], NO padding (32 MiB).
// x-boundary handled in-kernel via clamp + cndmask select.

// ---------------------------------------------------------------------------
// Cast planar fp32 (8ch) -> HP fp16 interleaved [vox][8].
// ---------------------------------------------------------------------------
__global__ __launch_bounds__(256) void cast_hp(const float* __restrict__ in,
                                               _Float16* __restrict__ hp)
{
    const int idx = blockIdx.x * 256 + threadIdx.x;
    half8 v;
    #pragma unroll
    for (int ic = 0; ic < 8; ++ic) v[ic] = (_Float16)in[(size_t)ic * VOX + idx];
    *(half8*)&hp[(size_t)idx * 8] = v;
}

// ---------------------------------------------------------------------------
// Dense 3x3x3 conv 8->8 + bias + relu via MFMA: HP in -> HP out.
// GEMM: D[8(pad16), VOX] = W[16, 216(pad224)] x X[216, VOX], K = tap*8+ic.
// Block = 4 waves over one (d,h) row of 128 voxels; wave: 2 n-tiles of 16.
// z/y-OOB taps (uniform per quad): zero A-frag; x-OOB (per lane): cndmask B.
// ---------------------------------------------------------------------------
__global__ __launch_bounds__(256) void conv8x8r_mfma(const _Float16* __restrict__ DP,
                                                     const float* __restrict__ wgt,
                                                     const float* __restrict__ bias,
                                                     _Float16* __restrict__ HO)
{
    __shared__ _Float16 Wr[16 * 28 * 8];   // [oc][tap][ic], zero-padded; 7168 B
    const int tid = threadIdx.x;
    for (int i = tid; i < 16 * 28; i += 256) ((half8*)Wr)[i] = half8{};
    __syncthreads();
    for (int i = tid; i < 8 * 216; i += 256) {
        const int oc = i / 216;
        const int rem = i - oc * 216;
        const int ic = rem / 27;
        const int tap = rem - ic * 27;
        Wr[(oc * 28 + tap) * 8 + ic] = (_Float16)wgt[i];
    }
    __syncthreads();

    const int b = ((blockIdx.x & 7) << 11) | (blockIdx.x >> 3);  // 16384 blocks
    const int h = b & 127;
    const int d = b >> 7;
    const int lane = tid & 63;
    const int wv   = tid >> 6;
    const int col  = lane & 15;
    const int q    = lane >> 4;

    half8 af[7];
    #pragma unroll
    for (int c = 0; c < 7; ++c)
        af[c] = *(const half8*)&Wr[(col * 28 + (c * 4 + q)) * 8];

    int rowb[7], cdx[7];
    const half8 zerov = {};
    #pragma unroll
    for (int c = 0; c < 7; ++c) {
        int tap = c * 4 + q; if (tap > 26) tap = 26;   // pad tap: A is zero
        const int dz = tap / 9 - 1;
        const int dy = (tap / 3) % 3 - 1;
        const int dx = tap - (tap / 3) * 3 - 1;
        const int z = d + dz, y = h + dy;
        const bool ok = ((unsigned)z < DSZ) && ((unsigned)y < DSZ);
        const int zc = min(max(z, 0), DSZ - 1);
        const int yc = min(max(y, 0), DSZ - 1);
        rowb[c] = ((zc << 7) + yc) << 7;               // voxel index of x=0
        cdx[c] = col + dx;
        if (!ok) af[c] = zerov;
    }

    #pragma unroll
    for (int t2 = 0; t2 < 2; ++t2) {
        const int xb = wv * 32 + t2 * 16;
        float4v acc = {0.0f, 0.0f, 0.0f, 0.0f};
        #pragma unroll
        for (int c = 0; c < 7; ++c) {
            const int xx = cdx[c] + xb;
            const bool okx = ((unsigned)xx < DSZ);
            const int xc = min(max(xx, 0), DSZ - 1);
            half8 bv = *(const half8*)(DP + (size_t)(rowb[c] + xc) * 8);
            bv = okx ? bv : zerov;
            acc = __builtin_amdgcn_mfma_f32_16x16x32_f16(af[c], bv, acc, 0, 0, 0);
        }
        if (q < 2) {                                    // rows q*4+r = oc 0..7
            const float4v bl = ((const float4v*)bias)[q];
            const int vox = (d << 14) + (h << 7) + xb + col;
            half4 hv;
            #pragma unroll
            for (int r = 0; r < 4; ++r)
                hv[r] = (_Float16)fmaxf(acc[r] + bl[r], 0.0f);
            *(half4*)&HO[(size_t)vox * 8 + q * 4] = hv;
        }
    }
}

// ---------------------------------------------------------------------------
// 8 -> 27 conv + L1 normalize via MFMA (unpadded HP in).
// Same structure as R6 winner; x-boundary now clamp + cndmask.
// ---------------------------------------------------------------------------
__global__ __launch_bounds__(256) void conv8x27n_mfma(const _Float16* __restrict__ HP,
                                                      const float* __restrict__ wgt,
                                                      _Float16* __restrict__ out)
{
    __shared__ _Float16 Wr[32 * 28 * 8];   // [oc][tap][ic], zero-padded; 14336 B
    const int tid = threadIdx.x;
    for (int i = tid; i < 32 * 28; i += 256) ((half8*)Wr)[i] = half8{};
    __syncthreads();
    for (int i = tid; i < 27 * 216; i += 256) {
        const int oc = i / 216;
        const int rem = i - oc * 216;
        const int ic = rem / 27;
        const int tap = rem - ic * 27;
        Wr[(oc * 28 + tap) * 8 + ic] = (_Float16)wgt[i];
    }
    __syncthreads();

    const int b = ((blockIdx.x & 7) << 11) | (blockIdx.x >> 3);  // 16384 blocks
    const int h = b & 127;
    const int d = b >> 7;
    const int lane = tid & 63;
    const int wv   = tid >> 6;
    const int col  = lane & 15;
    const int q    = lane >> 4;

    half8 af[2][7];
    #pragma unroll
    for (int t = 0; t < 2; ++t)
        #pragma unroll
        for (int c = 0; c < 7; ++c)
            af[t][c] = *(const half8*)&Wr[((t * 16 + col) * 28 + (c * 4 + q)) * 8];

    int rowb[7], cdx[7];
    const half8 zerov = {};
    #pragma unroll
    for (int c = 0; c < 7; ++c) {
        int tap = c * 4 + q; if (tap > 26) tap = 26;
        const int dz = tap / 9 - 1;
        const int dy = (tap / 3) % 3 - 1;
        const int dx = tap - (tap / 3) * 3 - 1;
        const int z = d + dz, y = h + dy;
        const bool ok = ((unsigned)z < DSZ) && ((unsigned)y < DSZ);
        const int zc = min(max(z, 0), DSZ - 1);
        const int yc = min(max(y, 0), DSZ - 1);
        rowb[c] = ((zc << 7) + yc) << 7;
        cdx[c] = col + dx;
        if (!ok) { af[0][c] = zerov; af[1][c] = zerov; }
    }

    #pragma unroll
    for (int t2 = 0; t2 < 2; ++t2) {
        const int xb = wv * 32 + t2 * 16;
        float4v acc0 = {0.0f, 0.0f, 0.0f, 0.0f};
        float4v acc1 = {0.0f, 0.0f, 0.0f, 0.0f};

        #pragma unroll
        for (int c = 0; c < 7; ++c) {
            const int xx = cdx[c] + xb;
            const bool okx = ((unsigned)xx < DSZ);
            const int xc = min(max(xx, 0), DSZ - 1);
            half8 bv = *(const half8*)(HP + (size_t)(rowb[c] + xc) * 8);
            bv = okx ? bv : zerov;
            acc0 = __builtin_amdgcn_mfma_f32_16x16x32_f16(af[0][c], bv, acc0, 0, 0, 0);
            acc1 = __builtin_amdgcn_mfma_f32_16x16x32_f16(af[1][c], bv, acc1, 0, 0, 0);
        }

        float s = 0.0f;
        #pragma unroll
        for (int r = 0; r < 4; ++r) {
            s += fabsf(acc0[r]);
            if (16 + q * 4 + r < 27) s += fabsf(acc1[r]);
        }
        s += __shfl_xor(s, 16);
        s += __shfl_xor(s, 32);
        const float rcp = 1.0f / fmaxf(s, 1e-12f);

        const int vox = (d << 14) + (h << 7) + xb + col;
        #pragma unroll
        for (int r = 0; r < 4; ++r) {
            out[(size_t)(q * 4 + r) * VOX + vox] = (_Float16)(acc0[r] * rcp);
            const int oc1 = 16 + q * 4 + r;
            if (oc1 < 27)
                out[(size_t)oc1 * VOX + vox] = (_Float16)(acc1[r] * rcp);
        }
    }
}

// ---------------------------------------------------------------------------
// Dense 3x3x3 conv 8->COUT planar fp32 (mid / out convs). R4 design.
// ---------------------------------------------------------------------------
template<int COUT, bool RELU>
__global__ __launch_bounds__(256) void conv3x3t(const float* __restrict__ in,
                                                const float* __restrict__ wgt,
                                                const float* __restrict__ bias,
                                                float* __restrict__ out)
{
    __shared__ float tile[8 * 3 * 4 * 130];
    const int tid = threadIdx.x;
    const int b = ((blockIdx.x & 7) << 10) | (blockIdx.x >> 3);
    const int d0 = b >> 6;
    const int h0 = (b & 63) << 1;
    const int x  = tid & 127;
    const int hi = tid >> 7;

    #pragma unroll 4
    for (int it = 0; it < 48; ++it) {
        const int r  = it * 2 + hi;
        const int ic = r / 12;
        const int s  = r - ic * 12;
        const int zz = s >> 2;
        const int yy = s & 3;
        const int z = d0 + zz - 1;
        const int y = h0 + yy - 1;
        float v = 0.0f;
        if (((unsigned)z < DSZ) && ((unsigned)y < DSZ))
            v = in[(size_t)ic * VOX + (z << 14) + (y << 7) + x];
        tile[r * 130 + 1 + x] = v;
    }
    if (tid < 192) tile[(tid >> 1) * 130 + (tid & 1) * 129] = 0.0f;
    __syncthreads();

    float acc[COUT];
    #pragma unroll
    for (int oc = 0; oc < COUT; ++oc) acc[oc] = bias[oc];

    #pragma unroll
    for (int ic = 0; ic < 8; ++ic) {
        #pragma unroll
        for (int kd = 0; kd < 3; ++kd) {
            #pragma unroll
            for (int kh = 0; kh < 3; ++kh) {
                const float* tp = &tile[((ic * 3 + kd) * 4 + (hi + kh)) * 130 + x];
                const float t0 = tp[0], t1 = tp[1], t2 = tp[2];
                #pragma unroll
                for (int oc = 0; oc < COUT; ++oc) {
                    const float* wp = &wgt[(oc * 8 + ic) * 27 + kd * 9 + kh * 3];
                    acc[oc] = fmaf(t0, wp[0], acc[oc]);
                    acc[oc] = fmaf(t1, wp[1], acc[oc]);
                    acc[oc] = fmaf(t2, wp[2], acc[oc]);
                }
            }
        }
    }

    const int idx = (d0 << 14) + ((h0 + hi) << 7) + x;
    #pragma unroll
    for (int oc = 0; oc < COUT; ++oc) {
        float r = acc[oc];
        if (RELU) r = fmaxf(r, 0.0f);
        out[(size_t)oc * VOX + idx] = r;
    }
}

// ---------------------------------------------------------------------------
// Adaptive stencil (no LDS, low VGPR) + XCD swizzle.
// ---------------------------------------------------------------------------
template<int C, bool TANH>
__global__ __launch_bounds__(256) void aconv(const float* __restrict__ in,
                                             const _Float16* __restrict__ wb,
                                             float* __restrict__ out)
{
    const int b = ((blockIdx.x & 7) << 10) | (blockIdx.x >> 3);  // 8192 blocks
    const int idx = b * 256 + threadIdx.x;
    const int w = idx & (DSZ - 1);
    const int h = (idx >> 7) & (DSZ - 1);
    const int d = idx >> 14;

    float wv[27];
    #pragma unroll
    for (int t = 0; t < 27; t++) wv[t] = (float)wb[(size_t)t * VOX + idx];

    float acc[C];
    #pragma unroll
    for (int c = 0; c < C; c++) acc[c] = 0.0f;

    #pragma unroll 1
    for (int kd = 0; kd < 3; kd++) {
        const int z = d + kd - 1;
        const bool okz = ((unsigned)z < DSZ);
        #pragma unroll
        for (int kh = 0; kh < 3; kh++) {
            const int y = h + kh - 1;
            const bool oky = okz && ((unsigned)y < DSZ);
            #pragma unroll
            for (int kw = 0; kw < 3; kw++) {
                const int xx = w + kw - 1;
                const bool ok = oky && ((unsigned)xx < DSZ);
                const int off = ok ? ((z * DSZ + y) * DSZ + xx) : idx;
                const int tap = kd * 9 + kh * 3 + kw;
                #pragma unroll
                for (int c = 0; c < C; c++) {
                    float t = in[(size_t)c * VOX + off];
                    acc[c] = fmaf(ok ? t : 0.0f, wv[tap], acc[c]);
                }
            }
        }
    }

    #pragma unroll
    for (int c = 0; c < C; c++) {
        float r = TANH ? tanhf(acc[c]) : acc[c];
        out[(size_t)c * VOX + idx] = r;
    }
}

// ---------------------------------------------------------------------------
// ws layout (236 MiB): R0 (64 MiB: two 32-MiB HP slots) | R1 (64 MiB: ditto)
//                      | WB (fp16, 108 MiB).
// ---------------------------------------------------------------------------
extern "C" void kernel_launch(void* const* d_in, const int* in_sizes, int n_in,
                              void* d_out, int out_size, void* d_ws, size_t ws_size,
                              hipStream_t stream)
{
    const float* x      = (const float*)d_in[0];
    const float* ac1_w1 = (const float*)d_in[1];
    const float* ac1_b1 = (const float*)d_in[2];
    const float* ac1_w2 = (const float*)d_in[3];
    const float* ac2_w1 = (const float*)d_in[4];
    const float* ac2_b1 = (const float*)d_in[5];
    const float* ac2_w2 = (const float*)d_in[6];
    const float* ac3_w1 = (const float*)d_in[7];
    const float* ac3_b1 = (const float*)d_in[8];
    const float* ac3_w2 = (const float*)d_in[9];
    const float* mid_w  = (const float*)d_in[10];
    const float* mid_b  = (const float*)d_in[11];
    const float* out_w  = (const float*)d_in[12];
    const float* out_b  = (const float*)d_in[13];
    float* out = (float*)d_out;

    char* ws = (char*)d_ws;
    const size_t MB = 1024 * 1024;
    float*     R0  = (float*)(ws);
    _Float16*  R0a = (_Float16*)(ws);               // HP slot
    _Float16*  R0b = (_Float16*)(ws + 32 * MB);     // HP slot
    float*     R1  = (float*)(ws + 64 * MB);
    _Float16*  R1a = (_Float16*)(ws + 64 * MB);
    _Float16*  R1b = (_Float16*)(ws + 96 * MB);
    _Float16*  WB  = (_Float16*)(ws + 128 * MB);
    float*     F1  = (float*)(ws);                  // 8 MiB, inside dead R0
    float*     F2  = (float*)(ws + 8 * MB);

    const dim3 blk(256);
    const dim3 gridT(VOX / 256);   // conv3x3t, aconv, cast_hp: 8192 blocks
    const dim3 gridM(VOX / 128);   // mfma kernels: 16384 blocks

    // ---- block 1 (input x; HP pair in R0) ----
    cast_hp<<<gridT, blk, 0, stream>>>(x, R0a);
    conv8x8r_mfma<<<gridM, blk, 0, stream>>>(R0a, ac1_w1, ac1_b1, R0b);
    conv8x27n_mfma<<<gridM, blk, 0, stream>>>(R0b, ac1_w2, WB);
    aconv<8, false><<<gridT, blk, 0, stream>>>(x,  WB, R1);
    aconv<8, false><<<gridT, blk, 0, stream>>>(R1, WB, R0);
    aconv<8, false><<<gridT, blk, 0, stream>>>(R0, WB, R1);
    // ---- mid conv ----
    conv3x3t<8, false><<<gridT, blk, 0, stream>>>(R1, mid_w, mid_b, R0);   // M = R0
    // ---- block 2 (on M; HP pair in R1) ----
    cast_hp<<<gridT, blk, 0, stream>>>(R0, R1a);
    conv8x8r_mfma<<<gridM, blk, 0, stream>>>(R1a, ac2_w1, ac2_b1, R1b);
    conv8x27n_mfma<<<gridM, blk, 0, stream>>>(R1b, ac2_w2, WB);
    aconv<8, false><<<gridT, blk, 0, stream>>>(R0, WB, R1);
    aconv<8, false><<<gridT, blk, 0, stream>>>(R1, WB, R0);
    aconv<8, false><<<gridT, blk, 0, stream>>>(R0, WB, R1);   // mid2 = R1
    // ---- block 3 (weights from mid2 = R1; HP pair in R0) ----
    cast_hp<<<gridT, blk, 0, stream>>>(R1, R0a);
    conv8x8r_mfma<<<gridM, blk, 0, stream>>>(R0a, ac3_w1, ac3_b1, R0b);
    conv8x27n_mfma<<<gridM, blk, 0, stream>>>(R0b, ac3_w2, WB);
    conv3x3t<1, false><<<gridT, blk, 0, stream>>>(R1, out_w, out_b, F1);
    aconv<1, false><<<gridT, blk, 0, stream>>>(F1, WB, F2);
    aconv<1, false><<<gridT, blk, 0, stream>>>(F2, WB, F1);
    aconv<1, true ><<<gridT, blk, 0, stream>>>(F1, WB, out);
}

// Round 9
// 983.367 us; speedup vs baseline: 4.5917x; 1.7181x over previous
//
#include <hip/hip_runtime.h>
#include <math.h>

#define DSZ 128
#define VOX (DSZ*DSZ*DSZ)  // 2,097,152 voxels

typedef _Float16 half8 __attribute__((ext_vector_type(8)));
typedef _Float16 half4 __attribute__((ext_vector_type(4)));
typedef float float4v __attribute__((ext_vector_type(4)));

// Interleaved fp16 tensor format: [vox][8] halves (32 MiB per 8-ch tensor).
// WB: planar fp16 [27][vox]. F/G: planar fp16 [vox].

// ---------------------------------------------------------------------------
// Cast planar fp32 (8ch) -> fp16 interleaved [vox][8].
// ---------------------------------------------------------------------------
__global__ __launch_bounds__(256) void cast_hp(const float* __restrict__ in,
                                               _Float16* __restrict__ hp)
{
    const int idx = blockIdx.x * 256 + threadIdx.x;
    half8 v;
    #pragma unroll
    for (int ic = 0; ic < 8; ++ic) v[ic] = (_Float16)in[(size_t)ic * VOX + idx];
    *(half8*)&hp[(size_t)idx * 8] = v;
}

// ---------------------------------------------------------------------------
// Dense 3x3x3 conv 8->8 (+bias, optional relu) via MFMA, interleaved in/out.
// GEMM: D[16, VOX] = W[16,224] x X[224, VOX], K = tap*8+ic (zero-padded).
// ---------------------------------------------------------------------------
template<bool RELU>
__global__ __launch_bounds__(256) void conv8x8_mfma(const _Float16* __restrict__ DP,
                                                    const float* __restrict__ wgt,
                                                    const float* __restrict__ bias,
                                                    _Float16* __restrict__ HO)
{
    __shared__ _Float16 Wr[16 * 28 * 8];   // [oc][tap][ic], zero-padded
    const int tid = threadIdx.x;
    for (int i = tid; i < 16 * 28; i += 256) ((half8*)Wr)[i] = half8{};
    __syncthreads();
    for (int i = tid; i < 8 * 216; i += 256) {
        const int oc = i / 216;
        const int rem = i - oc * 216;
        const int ic = rem / 27;
        const int tap = rem - ic * 27;
        Wr[(oc * 28 + tap) * 8 + ic] = (_Float16)wgt[i];
    }
    __syncthreads();

    const int b = ((blockIdx.x & 7) << 11) | (blockIdx.x >> 3);  // 16384 blocks
    const int h = b & 127;
    const int d = b >> 7;
    const int lane = tid & 63;
    const int wv   = tid >> 6;
    const int col  = lane & 15;
    const int q    = lane >> 4;

    half8 af[7];
    #pragma unroll
    for (int c = 0; c < 7; ++c)
        af[c] = *(const half8*)&Wr[(col * 28 + (c * 4 + q)) * 8];

    int rowb[7], cdx[7];
    const half8 zerov = {};
    #pragma unroll
    for (int c = 0; c < 7; ++c) {
        int tap = c * 4 + q; if (tap > 26) tap = 26;   // pad tap: A is zero
        const int dz = tap / 9 - 1;
        const int dy = (tap / 3) % 3 - 1;
        const int dx = tap - (tap / 3) * 3 - 1;
        const int z = d + dz, y = h + dy;
        const bool ok = ((unsigned)z < DSZ) && ((unsigned)y < DSZ);
        const int zc = min(max(z, 0), DSZ - 1);
        const int yc = min(max(y, 0), DSZ - 1);
        rowb[c] = ((zc << 7) + yc) << 7;
        cdx[c] = col + dx;
        if (!ok) af[c] = zerov;
    }

    #pragma unroll
    for (int t2 = 0; t2 < 2; ++t2) {
        const int xb = wv * 32 + t2 * 16;
        float4v acc = {0.0f, 0.0f, 0.0f, 0.0f};
        #pragma unroll
        for (int c = 0; c < 7; ++c) {
            const int xx = cdx[c] + xb;
            const bool okx = ((unsigned)xx < DSZ);
            const int xc = min(max(xx, 0), DSZ - 1);
            half8 bv = *(const half8*)(DP + (size_t)(rowb[c] + xc) * 8);
            bv = okx ? bv : zerov;
            acc = __builtin_amdgcn_mfma_f32_16x16x32_f16(af[c], bv, acc, 0, 0, 0);
        }
        if (q < 2) {                                    // rows q*4+r = oc 0..7
            const float4v bl = ((const float4v*)bias)[q];
            const int vox = (d << 14) + (h << 7) + xb + col;
            half4 hv;
            #pragma unroll
            for (int r = 0; r < 4; ++r) {
                float v = acc[r] + bl[r];
                if (RELU) v = fmaxf(v, 0.0f);
                hv[r] = (_Float16)v;
            }
            *(half4*)&HO[(size_t)vox * 8 + q * 4] = hv;
        }
    }
}

// ---------------------------------------------------------------------------
// Dense 3x3x3 conv 8->1 (+bias) via MFMA, interleaved in -> planar fp16 out.
// ---------------------------------------------------------------------------
__global__ __launch_bounds__(256) void conv8x1_mfma(const _Float16* __restrict__ DP,
                                                    const float* __restrict__ wgt,
                                                    const float* __restrict__ bias,
                                                    _Float16* __restrict__ F)
{
    __shared__ _Float16 Wr[16 * 28 * 8];   // only oc 0 nonzero
    const int tid = threadIdx.x;
    for (int i = tid; i < 16 * 28; i += 256) ((half8*)Wr)[i] = half8{};
    __syncthreads();
    for (int i = tid; i < 216; i += 256) {
        const int ic = i / 27;
        const int tap = i - ic * 27;
        Wr[tap * 8 + ic] = (_Float16)wgt[i];   // oc = 0
    }
    __syncthreads();

    const int b = ((blockIdx.x & 7) << 11) | (blockIdx.x >> 3);
    const int h = b & 127;
    const int d = b >> 7;
    const int lane = tid & 63;
    const int wv   = tid >> 6;
    const int col  = lane & 15;
    const int q    = lane >> 4;

    half8 af[7];
    #pragma unroll
    for (int c = 0; c < 7; ++c)
        af[c] = *(const half8*)&Wr[(col * 28 + (c * 4 + q)) * 8];

    int rowb[7], cdx[7];
    const half8 zerov = {};
    #pragma unroll
    for (int c = 0; c < 7; ++c) {
        int tap = c * 4 + q; if (tap > 26) tap = 26;
        const int dz = tap / 9 - 1;
        const int dy = (tap / 3) % 3 - 1;
        const int dx = tap - (tap / 3) * 3 - 1;
        const int z = d + dz, y = h + dy;
        const bool ok = ((unsigned)z < DSZ) && ((unsigned)y < DSZ);
        const int zc = min(max(z, 0), DSZ - 1);
        const int yc = min(max(y, 0), DSZ - 1);
        rowb[c] = ((zc << 7) + yc) << 7;
        cdx[c] = col + dx;
        if (!ok) af[c] = zerov;
    }

    const float b0 = bias[0];
    #pragma unroll
    for (int t2 = 0; t2 < 2; ++t2) {
        const int xb = wv * 32 + t2 * 16;
        float4v acc = {0.0f, 0.0f, 0.0f, 0.0f};
        #pragma unroll
        for (int c = 0; c < 7; ++c) {
            const int xx = cdx[c] + xb;
            const bool okx = ((unsigned)xx < DSZ);
            const int xc = min(max(xx, 0), DSZ - 1);
            half8 bv = *(const half8*)(DP + (size_t)(rowb[c] + xc) * 8);
            bv = okx ? bv : zerov;
            acc = __builtin_amdgcn_mfma_f32_16x16x32_f16(af[c], bv, acc, 0, 0, 0);
        }
        if (q == 0) {                                   // row 0 = oc 0
            const int vox = (d << 14) + (h << 7) + xb + col;
            F[vox] = (_Float16)(acc[0] + b0);
        }
    }
}

// ---------------------------------------------------------------------------
// 8 -> 27 conv + L1 normalize via MFMA (interleaved fp16 in, planar fp16 WB out).
// ---------------------------------------------------------------------------
__global__ __launch_bounds__(256) void conv8x27n_mfma(const _Float16* __restrict__ HP,
                                                      const float* __restrict__ wgt,
                                                      _Float16* __restrict__ out)
{
    __shared__ _Float16 Wr[32 * 28 * 8];
    const int tid = threadIdx.x;
    for (int i = tid; i < 32 * 28; i += 256) ((half8*)Wr)[i] = half8{};
    __syncthreads();
    for (int i = tid; i < 27 * 216; i += 256) {
        const int oc = i / 216;
        const int rem = i - oc * 216;
        const int ic = rem / 27;
        const int tap = rem - ic * 27;
        Wr[(oc * 28 + tap) * 8 + ic] = (_Float16)wgt[i];
    }
    __syncthreads();

    const int b = ((blockIdx.x & 7) << 11) | (blockIdx.x >> 3);
    const int h = b & 127;
    const int d = b >> 7;
    const int lane = tid & 63;
    const int wv   = tid >> 6;
    const int col  = lane & 15;
    const int q    = lane >> 4;

    half8 af[2][7];
    #pragma unroll
    for (int t = 0; t < 2; ++t)
        #pragma unroll
        for (int c = 0; c < 7; ++c)
            af[t][c] = *(const half8*)&Wr[((t * 16 + col) * 28 + (c * 4 + q)) * 8];

    int rowb[7], cdx[7];
    const half8 zerov = {};
    #pragma unroll
    for (int c = 0; c < 7; ++c) {
        int tap = c * 4 + q; if (tap > 26) tap = 26;
        const int dz = tap / 9 - 1;
        const int dy = (tap / 3) % 3 - 1;
        const int dx = tap - (tap / 3) * 3 - 1;
        const int z = d + dz, y = h + dy;
        const bool ok = ((unsigned)z < DSZ) && ((unsigned)y < DSZ);
        const int zc = min(max(z, 0), DSZ - 1);
        const int yc = min(max(y, 0), DSZ - 1);
        rowb[c] = ((zc << 7) + yc) << 7;
        cdx[c] = col + dx;
        if (!ok) { af[0][c] = zerov; af[1][c] = zerov; }
    }

    #pragma unroll
    for (int t2 = 0; t2 < 2; ++t2) {
        const int xb = wv * 32 + t2 * 16;
        float4v acc0 = {0.0f, 0.0f, 0.0f, 0.0f};
        float4v acc1 = {0.0f, 0.0f, 0.0f, 0.0f};

        #pragma unroll
        for (int c = 0; c < 7; ++c) {
            const int xx = cdx[c] + xb;
            const bool okx = ((unsigned)xx < DSZ);
            const int xc = min(max(xx, 0), DSZ - 1);
            half8 bv = *(const half8*)(HP + (size_t)(rowb[c] + xc) * 8);
            bv = okx ? bv : zerov;
            acc0 = __builtin_amdgcn_mfma_f32_16x16x32_f16(af[0][c], bv, acc0, 0, 0, 0);
            acc1 = __builtin_amdgcn_mfma_f32_16x16x32_f16(af[1][c], bv, acc1, 0, 0, 0);
        }

        float s = 0.0f;
        #pragma unroll
        for (int r = 0; r < 4; ++r) {
            s += fabsf(acc0[r]);
            if (16 + q * 4 + r < 27) s += fabsf(acc1[r]);
        }
        s += __shfl_xor(s, 16);
        s += __shfl_xor(s, 32);
        const float rcp = 1.0f / fmaxf(s, 1e-12f);

        const int vox = (d << 14) + (h << 7) + xb + col;
        #pragma unroll
        for (int r = 0; r < 4; ++r) {
            out[(size_t)(q * 4 + r) * VOX + vox] = (_Float16)(acc0[r] * rcp);
            const int oc1 = 16 + q * 4 + r;
            if (oc1 < 27)
                out[(size_t)oc1 * VOX + vox] = (_Float16)(acc1[r] * rcp);
        }
    }
}

// ---------------------------------------------------------------------------
// Adaptive stencil, 8ch interleaved fp16 in/out: ONE half8 load per tap
// (clamped address), OOB handled by zeroing the weight. fp32 accumulate.
// ---------------------------------------------------------------------------
__global__ __launch_bounds__(256) void aconv8i(const _Float16* __restrict__ in,
                                               const _Float16* __restrict__ wb,
                                               _Float16* __restrict__ out)
{
    const int b = ((blockIdx.x & 7) << 10) | (blockIdx.x >> 3);  // 8192 blocks
    const int idx = b * 256 + threadIdx.x;
    const int w = idx & 127;
    const int h = (idx >> 7) & 127;
    const int d = idx >> 14;

    float wv[27];
    #pragma unroll
    for (int t = 0; t < 27; t++) wv[t] = (float)wb[(size_t)t * VOX + idx];

    float acc[8];
    #pragma unroll
    for (int c = 0; c < 8; c++) acc[c] = 0.0f;

    #pragma unroll
    for (int kd = 0; kd < 3; kd++) {
        const int z = d + kd - 1;
        const bool okz = ((unsigned)z < DSZ);
        const int zc = min(max(z, 0), DSZ - 1);
        #pragma unroll
        for (int kh = 0; kh < 3; kh++) {
            const int y = h + kh - 1;
            const bool okzy = okz && ((unsigned)y < DSZ);
            const int yc = min(max(y, 0), DSZ - 1);
            const int rowb = ((zc << 7) + yc) << 7;
            #pragma unroll
            for (int kw = 0; kw < 3; kw++) {
                const int xx = w + kw - 1;
                const bool ok = okzy && ((unsigned)xx < DSZ);
                const int xc = min(max(xx, 0), DSZ - 1);
                const float wt = ok ? wv[kd * 9 + kh * 3 + kw] : 0.0f;
                const half8 hv = *(const half8*)(in + (size_t)(rowb + xc) * 8);
                #pragma unroll
                for (int c = 0; c < 8; c++)
                    acc[c] = fmaf((float)hv[c], wt, acc[c]);
            }
        }
    }

    half8 o;
    #pragma unroll
    for (int c = 0; c < 8; c++) o[c] = (_Float16)acc[c];
    *(half8*)&out[(size_t)idx * 8] = o;
}

// ---------------------------------------------------------------------------
// Adaptive stencil, 1ch planar fp16 in; out fp16 (or fp32+tanh for final).
// ---------------------------------------------------------------------------
template<bool TANH>
__global__ __launch_bounds__(256) void aconv1h(const _Float16* __restrict__ in,
                                               const _Float16* __restrict__ wb,
                                               _Float16* __restrict__ outh,
                                               float* __restrict__ outf)
{
    const int b = ((blockIdx.x & 7) << 10) | (blockIdx.x >> 3);
    const int idx = b * 256 + threadIdx.x;
    const int w = idx & 127;
    const int h = (idx >> 7) & 127;
    const int d = idx >> 14;

    float wv[27];
    #pragma unroll
    for (int t = 0; t < 27; t++) wv[t] = (float)wb[(size_t)t * VOX + idx];

    float acc = 0.0f;
    #pragma unroll
    for (int kd = 0; kd < 3; kd++) {
        const int z = d + kd - 1;
        const bool okz = ((unsigned)z < DSZ);
        const int zc = min(max(z, 0), DSZ - 1);
        #pragma unroll
        for (int kh = 0; kh < 3; kh++) {
            const int y = h + kh - 1;
            const bool okzy = okz && ((unsigned)y < DSZ);
            const int yc = min(max(y, 0), DSZ - 1);
            const int rowb = ((zc << 7) + yc) << 7;
            #pragma unroll
            for (int kw = 0; kw < 3; kw++) {
                const int xx = w + kw - 1;
                const bool ok = okzy && ((unsigned)xx < DSZ);
                const int xc = min(max(xx, 0), DSZ - 1);
                const float wt = ok ? wv[kd * 9 + kh * 3 + kw] : 0.0f;
                acc = fmaf((float)in[rowb + xc], wt, acc);
            }
        }
    }

    if (TANH) outf[idx] = tanhf(acc);
    else      outh[idx] = (_Float16)acc;
}

// ---------------------------------------------------------------------------
// ws layout (236 MiB): S0..S3 = four 32-MiB interleaved-fp16 slots,
// WB (fp16 planar, 108 MiB) at +128 MiB. F/G (4 MiB) live in dead slots.
// ---------------------------------------------------------------------------
extern "C" void kernel_launch(void* const* d_in, const int* in_sizes, int n_in,
                              void* d_out, int out_size, void* d_ws, size_t ws_size,
                              hipStream_t stream)
{
    const float* x      = (const float*)d_in[0];
    const float* ac1_w1 = (const float*)d_in[1];
    const float* ac1_b1 = (const float*)d_in[2];
    const float* ac1_w2 = (const float*)d_in[3];
    const float* ac2_w1 = (const float*)d_in[4];
    const float* ac2_b1 = (const float*)d_in[5];
    const float* ac2_w2 = (const float*)d_in[6];
    const float* ac3_w1 = (const float*)d_in[7];
    const float* ac3_b1 = (const float*)d_in[8];
    const float* ac3_w2 = (const float*)d_in[9];
    const float* mid_w  = (const float*)d_in[10];
    const float* mid_b  = (const float*)d_in[11];
    const float* out_w  = (const float*)d_in[12];
    const float* out_b  = (const float*)d_in[13];
    float* out = (float*)d_out;

    char* ws = (char*)d_ws;
    const size_t MB = 1024 * 1024;
    _Float16* S0 = (_Float16*)(ws);
    _Float16* S1 = (_Float16*)(ws + 32 * MB);
    _Float16* S2 = (_Float16*)(ws + 64 * MB);
    _Float16* S3 = (_Float16*)(ws + 96 * MB);
    _Float16* WB = (_Float16*)(ws + 128 * MB);

    const dim3 blk(256);
    const dim3 gridT(VOX / 256);   // cast, aconv: 8192 blocks
    const dim3 gridM(VOX / 128);   // mfma kernels: 16384 blocks

    // ---- block 1 ----
    cast_hp<<<gridT, blk, 0, stream>>>(x, S0);                       // X16 = S0
    conv8x8_mfma<true ><<<gridM, blk, 0, stream>>>(S0, ac1_w1, ac1_b1, S1);   // H1
    conv8x27n_mfma<<<gridM, blk, 0, stream>>>(S1, ac1_w2, WB);
    aconv8i<<<gridT, blk, 0, stream>>>(S0, WB, S2);
    aconv8i<<<gridT, blk, 0, stream>>>(S2, WB, S3);
    aconv8i<<<gridT, blk, 0, stream>>>(S3, WB, S2);                  // C1 = S2
    // ---- mid conv ----
    conv8x8_mfma<false><<<gridM, blk, 0, stream>>>(S2, mid_w, mid_b, S1);     // M = S1
    // ---- block 2 ----
    conv8x8_mfma<true ><<<gridM, blk, 0, stream>>>(S1, ac2_w1, ac2_b1, S0);   // H2
    conv8x27n_mfma<<<gridM, blk, 0, stream>>>(S0, ac2_w2, WB);
    aconv8i<<<gridT, blk, 0, stream>>>(S1, WB, S2);
    aconv8i<<<gridT, blk, 0, stream>>>(S2, WB, S3);
    aconv8i<<<gridT, blk, 0, stream>>>(S3, WB, S2);                  // mid2 = S2
    // ---- block 3 (weights from mid2 = S2) ----
    conv8x8_mfma<true ><<<gridM, blk, 0, stream>>>(S2, ac3_w1, ac3_b1, S0);   // H3
    conv8x27n_mfma<<<gridM, blk, 0, stream>>>(S0, ac3_w2, WB);
    conv8x1_mfma<<<gridM, blk, 0, stream>>>(S2, out_w, out_b, S1);   // F1 = S1
    aconv1h<false><<<gridT, blk, 0, stream>>>(S1, WB, S3, nullptr);  // G1 = S3
    aconv1h<false><<<gridT, blk, 0, stream>>>(S3, WB, S0, nullptr);  // G2 = S0
    aconv1h<true ><<<gridT, blk, 0, stream>>>(S0, WB, nullptr, out); // final + tanh
}

// Round 10
// 961.102 us; speedup vs baseline: 4.6981x; 1.0232x over previous
//
#include <hip/hip_runtime.h>
#include <math.h>

#define DSZ 128
#define VOX (DSZ*DSZ*DSZ)  // 2,097,152 voxels
#define PROW 130           // padded x row: px = x+1, pads px=0,129 zeroed

typedef _Float16 half8 __attribute__((ext_vector_type(8)));
typedef _Float16 half4 __attribute__((ext_vector_type(4)));
typedef _Float16 half2v __attribute__((ext_vector_type(2)));
typedef float float4v __attribute__((ext_vector_type(4)));

// Padded interleaved fp16 tensor: slot(z,y,px) = ((z*128+y)*130+px); halves = slot*8.
// Size per tensor: 16384*130*8*2 = 34,078,720 B (32.5 MiB).
// WB: interleaved [vox][32] halves (27 taps + 5 pad), 128 MiB.
__device__ __forceinline__ int pslot(int z, int y, int px) {
    return ((z << 7) + y) * PROW + px;
}

// ---------------------------------------------------------------------------
// Zero x-pad columns of a padded interleaved tensor (ws re-poisoned each call).
// ---------------------------------------------------------------------------
__global__ __launch_bounds__(256) void zero_pad(_Float16* __restrict__ P)
{
    const int t = blockIdx.x * 256 + threadIdx.x;   // 16384 (z,y) rows
    half8 zz = {};
    *(half8*)&P[(size_t)t * PROW * 8] = zz;            // px = 0
    *(half8*)&P[(size_t)t * PROW * 8 + 129 * 8] = zz;  // px = 129
}

// ---------------------------------------------------------------------------
// Cast planar fp32 (8ch) -> padded interleaved fp16.
// ---------------------------------------------------------------------------
__global__ __launch_bounds__(256) void cast_hp(const float* __restrict__ in,
                                               _Float16* __restrict__ hp)
{
    const int idx = blockIdx.x * 256 + threadIdx.x;
    const int x = idx & 127;
    const int row = idx >> 7;                       // (z,y)
    half8 v;
    #pragma unroll
    for (int ic = 0; ic < 8; ++ic) v[ic] = (_Float16)in[(size_t)ic * VOX + idx];
    *(half8*)&hp[((size_t)row * PROW + x + 1) * 8] = v;
}

// ---------------------------------------------------------------------------
// Dense 3x3x3 conv 8->8 (+bias, opt relu) via MFMA, padded interleaved in/out.
// z/y-OOB taps: zero A-frag (weights); x-OOB: pad columns read zero.
// ---------------------------------------------------------------------------
template<bool RELU>
__global__ __launch_bounds__(256) void conv8x8_mfma(const _Float16* __restrict__ DP,
                                                    const float* __restrict__ wgt,
                                                    const float* __restrict__ bias,
                                                    _Float16* __restrict__ HO)
{
    __shared__ _Float16 Wr[16 * 29 * 8];   // [oc][tap][ic], stride 29 (bank spread)
    const int tid = threadIdx.x;
    for (int i = tid; i < 16 * 29; i += 256) ((half8*)Wr)[i] = half8{};
    __syncthreads();
    for (int i = tid; i < 8 * 216; i += 256) {
        const int oc = i / 216;
        const int rem = i - oc * 216;
        const int ic = rem / 27;
        const int tap = rem - ic * 27;
        Wr[(oc * 29 + tap) * 8 + ic] = (_Float16)wgt[i];
    }
    __syncthreads();

    const int b = ((blockIdx.x & 7) << 11) | (blockIdx.x >> 3);  // 16384 blocks
    const int h = b & 127;
    const int d = b >> 7;
    const int lane = tid & 63;
    const int wv   = tid >> 6;
    const int col  = lane & 15;
    const int q    = lane >> 4;

    half8 af[7];
    #pragma unroll
    for (int c = 0; c < 7; ++c)
        af[c] = *(const half8*)&Wr[(col * 29 + (c * 4 + q)) * 8];

    int rowcol[7];
    const half8 zerov = {};
    #pragma unroll
    for (int c = 0; c < 7; ++c) {
        int tap = c * 4 + q; if (tap > 26) tap = 26;   // pad tap: A is zero
        const int dz = tap / 9 - 1;
        const int dy = (tap / 3) % 3 - 1;
        const int dx = tap - (tap / 3) * 3 - 1;
        const int z = d + dz, y = h + dy;
        const bool ok = ((unsigned)z < DSZ) && ((unsigned)y < DSZ);
        const int zc = min(max(z, 0), DSZ - 1);
        const int yc = min(max(y, 0), DSZ - 1);
        rowcol[c] = pslot(zc, yc, dx + 1) + col;       // + x later
        if (!ok) af[c] = zerov;
    }

    #pragma unroll
    for (int t2 = 0; t2 < 2; ++t2) {
        const int xb = wv * 32 + t2 * 16;
        float4v acc = {0.0f, 0.0f, 0.0f, 0.0f};
        #pragma unroll
        for (int c = 0; c < 7; ++c) {
            const half8 bv = *(const half8*)(DP + (size_t)(rowcol[c] + xb) * 8);
            acc = __builtin_amdgcn_mfma_f32_16x16x32_f16(af[c], bv, acc, 0, 0, 0);
        }
        if (q < 2) {                                    // rows q*4+r = oc 0..7
            const float4v bl = ((const float4v*)bias)[q];
            half4 hv;
            #pragma unroll
            for (int r = 0; r < 4; ++r) {
                float v = acc[r] + bl[r];
                if (RELU) v = fmaxf(v, 0.0f);
                hv[r] = (_Float16)v;
            }
            *(half4*)&HO[(size_t)pslot(d, h, xb + col + 1) * 8 + q * 4] = hv;
        }
    }
}

// ---------------------------------------------------------------------------
// Dense 3x3x3 conv 8->1 (+bias) via MFMA, padded interleaved in -> planar fp16.
// ---------------------------------------------------------------------------
__global__ __launch_bounds__(256) void conv8x1_mfma(const _Float16* __restrict__ DP,
                                                    const float* __restrict__ wgt,
                                                    const float* __restrict__ bias,
                                                    _Float16* __restrict__ F)
{
    __shared__ _Float16 Wr[16 * 29 * 8];   // only oc 0 nonzero
    const int tid = threadIdx.x;
    for (int i = tid; i < 16 * 29; i += 256) ((half8*)Wr)[i] = half8{};
    __syncthreads();
    for (int i = tid; i < 216; i += 256) {
        const int ic = i / 27;
        const int tap = i - ic * 27;
        Wr[tap * 8 + ic] = (_Float16)wgt[i];   // oc = 0
    }
    __syncthreads();

    const int b = ((blockIdx.x & 7) << 11) | (blockIdx.x >> 3);
    const int h = b & 127;
    const int d = b >> 7;
    const int lane = tid & 63;
    const int wv   = tid >> 6;
    const int col  = lane & 15;
    const int q    = lane >> 4;

    half8 af[7];
    #pragma unroll
    for (int c = 0; c < 7; ++c)
        af[c] = *(const half8*)&Wr[(col * 29 + (c * 4 + q)) * 8];

    int rowcol[7];
    const half8 zerov = {};
    #pragma unroll
    for (int c = 0; c < 7; ++c) {
        int tap = c * 4 + q; if (tap > 26) tap = 26;
        const int dz = tap / 9 - 1;
        const int dy = (tap / 3) % 3 - 1;
        const int dx = tap - (tap / 3) * 3 - 1;
        const int z = d + dz, y = h + dy;
        const bool ok = ((unsigned)z < DSZ) && ((unsigned)y < DSZ);
        const int zc = min(max(z, 0), DSZ - 1);
        const int yc = min(max(y, 0), DSZ - 1);
        rowcol[c] = pslot(zc, yc, dx + 1) + col;
        if (!ok) af[c] = zerov;
    }

    const float b0 = bias[0];
    #pragma unroll
    for (int t2 = 0; t2 < 2; ++t2) {
        const int xb = wv * 32 + t2 * 16;
        float4v acc = {0.0f, 0.0f, 0.0f, 0.0f};
        #pragma unroll
        for (int c = 0; c < 7; ++c) {
            const half8 bv = *(const half8*)(DP + (size_t)(rowcol[c] + xb) * 8);
            acc = __builtin_amdgcn_mfma_f32_16x16x32_f16(af[c], bv, acc, 0, 0, 0);
        }
        if (q == 0) {
            const int vox = (d << 14) + (h << 7) + xb + col;
            F[vox] = (_Float16)(acc[0] + b0);
        }
    }
}

// ---------------------------------------------------------------------------
// 8 -> 27 conv + L1 normalize via MFMA; padded interleaved in,
// WB out interleaved [vox][32] (taps 27..31 are pad; tile1/q=3 writes zeros).
// ---------------------------------------------------------------------------
__global__ __launch_bounds__(256) void conv8x27n_mfma(const _Float16* __restrict__ HP,
                                                      const float* __restrict__ wgt,
                                                      _Float16* __restrict__ WB)
{
    __shared__ _Float16 Wr[32 * 29 * 8];
    const int tid = threadIdx.x;
    for (int i = tid; i < 32 * 29; i += 256) ((half8*)Wr)[i] = half8{};
    __syncthreads();
    for (int i = tid; i < 27 * 216; i += 256) {
        const int oc = i / 216;
        const int rem = i - oc * 216;
        const int ic = rem / 27;
        const int tap = rem - ic * 27;
        Wr[(oc * 29 + tap) * 8 + ic] = (_Float16)wgt[i];
    }
    __syncthreads();

    const int b = ((blockIdx.x & 7) << 11) | (blockIdx.x >> 3);
    const int h = b & 127;
    const int d = b >> 7;
    const int lane = tid & 63;
    const int wv   = tid >> 6;
    const int col  = lane & 15;
    const int q    = lane >> 4;

    half8 af[2][7];
    #pragma unroll
    for (int t = 0; t < 2; ++t)
        #pragma unroll
        for (int c = 0; c < 7; ++c)
            af[t][c] = *(const half8*)&Wr[((t * 16 + col) * 29 + (c * 4 + q)) * 8];

    int rowcol[7];
    const half8 zerov = {};
    #pragma unroll
    for (int c = 0; c < 7; ++c) {
        int tap = c * 4 + q; if (tap > 26) tap = 26;
        const int dz = tap / 9 - 1;
        const int dy = (tap / 3) % 3 - 1;
        const int dx = tap - (tap / 3) * 3 - 1;
        const int z = d + dz, y = h + dy;
        const bool ok = ((unsigned)z < DSZ) && ((unsigned)y < DSZ);
        const int zc = min(max(z, 0), DSZ - 1);
        const int yc = min(max(y, 0), DSZ - 1);
        rowcol[c] = pslot(zc, yc, dx + 1) + col;
        if (!ok) { af[0][c] = zerov; af[1][c] = zerov; }
    }

    #pragma unroll
    for (int t2 = 0; t2 < 2; ++t2) {
        const int xb = wv * 32 + t2 * 16;
        float4v acc0 = {0.0f, 0.0f, 0.0f, 0.0f};
        float4v acc1 = {0.0f, 0.0f, 0.0f, 0.0f};

        #pragma unroll
        for (int c = 0; c < 7; ++c) {
            const half8 bv = *(const half8*)(HP + (size_t)(rowcol[c] + xb) * 8);
            acc0 = __builtin_amdgcn_mfma_f32_16x16x32_f16(af[0][c], bv, acc0, 0, 0, 0);
            acc1 = __builtin_amdgcn_mfma_f32_16x16x32_f16(af[1][c], bv, acc1, 0, 0, 0);
        }

        float s = 0.0f;
        #pragma unroll
        for (int r = 0; r < 4; ++r) {
            s += fabsf(acc0[r]);
            if (16 + q * 4 + r < 27) s += fabsf(acc1[r]);   // q=3 tile1 rows are pad
        }
        s += __shfl_xor(s, 16);
        s += __shfl_xor(s, 32);
        const float rcp = 1.0f / fmaxf(s, 1e-12f);

        const size_t base = (size_t)((d << 14) + (h << 7) + xb + col) * 32;
        half4 o0, o1;
        #pragma unroll
        for (int r = 0; r < 4; ++r) {
            o0[r] = (_Float16)(acc0[r] * rcp);
            o1[r] = (_Float16)(acc1[r] * rcp);   // pad rows: acc1==0 -> writes 0
        }
        *(half4*)&WB[base + q * 4]      = o0;
        *(half4*)&WB[base + 16 + q * 4] = o1;
    }
}

// ---------------------------------------------------------------------------
// Adaptive stencil, 8ch padded interleaved in/out. WB interleaved [vox][32].
// z/y OOB: clamp row + zero weight. x OOB: pad columns read zero.
// fp16 pk math (error contracts through the remaining network).
// ---------------------------------------------------------------------------
__global__ __launch_bounds__(256) void aconv8i(const _Float16* __restrict__ in,
                                               const _Float16* __restrict__ wb,
                                               _Float16* __restrict__ out)
{
    const int b = ((blockIdx.x & 7) << 10) | (blockIdx.x >> 3);  // 8192 blocks
    const int idx = b * 256 + threadIdx.x;
    const int w = idx & 127;
    const int h = (idx >> 7) & 127;
    const int d = idx >> 14;

    const size_t wbb = (size_t)idx * 32;
    const half8 wa = *(const half8*)(wb + wbb);
    const half8 wbv = *(const half8*)(wb + wbb + 8);
    const half8 wc = *(const half8*)(wb + wbb + 16);
    const half8 wd = *(const half8*)(wb + wbb + 24);

    half2v a4[4];
    #pragma unroll
    for (int j = 0; j < 4; ++j) a4[j] = half2v{};

    #pragma unroll
    for (int kd = 0; kd < 3; kd++) {
        const int z = d + kd - 1;
        const bool okz = ((unsigned)z < DSZ);
        const int zc = min(max(z, 0), DSZ - 1);
        #pragma unroll
        for (int kh = 0; kh < 3; kh++) {
            const int y = h + kh - 1;
            const bool ok = okz && ((unsigned)y < DSZ);
            const int yc = min(max(y, 0), DSZ - 1);
            const _Float16* rp = in + (size_t)(((zc << 7) + yc) * PROW + w) * 8;
            #pragma unroll
            for (int kw = 0; kw < 3; kw++) {
                const int tap = kd * 9 + kh * 3 + kw;
                _Float16 wt = (tap < 8) ? wa[tap] : (tap < 16) ? wbv[tap - 8]
                            : (tap < 24) ? wc[tap - 16] : wd[tap - 24];
                wt = ok ? wt : (_Float16)0.0f;
                half2v w2; w2[0] = wt; w2[1] = wt;
                const half8 hv = *(const half8*)(rp + kw * 8);   // px = w+kw
                const half2v* h2 = (const half2v*)&hv;
                #pragma unroll
                for (int j = 0; j < 4; ++j)
                    a4[j] += h2[j] * w2;                          // v_pk_fma_f16
            }
        }
    }

    half8 o;
    #pragma unroll
    for (int j = 0; j < 4; ++j) { o[2 * j] = a4[j][0]; o[2 * j + 1] = a4[j][1]; }
    *(half8*)&out[(size_t)pslot(d, h, w + 1) * 8] = o;
}

// ---------------------------------------------------------------------------
// Adaptive stencil, 1ch planar fp16 in (values subnormal-small: fp32 math).
// ---------------------------------------------------------------------------
template<bool TANH>
__global__ __launch_bounds__(256) void aconv1h(const _Float16* __restrict__ in,
                                               const _Float16* __restrict__ wb,
                                               _Float16* __restrict__ outh,
                                               float* __restrict__ outf)
{
    const int b = ((blockIdx.x & 7) << 10) | (blockIdx.x >> 3);
    const int idx = b * 256 + threadIdx.x;
    const int w = idx & 127;
    const int h = (idx >> 7) & 127;
    const int d = idx >> 14;

    const size_t wbb = (size_t)idx * 32;
    const half8 wa = *(const half8*)(wb + wbb);
    const half8 wbv = *(const half8*)(wb + wbb + 8);
    const half8 wc = *(const half8*)(wb + wbb + 16);
    const half8 wd = *(const half8*)(wb + wbb + 24);

    float acc = 0.0f;
    #pragma unroll
    for (int kd = 0; kd < 3; kd++) {
        const int z = d + kd - 1;
        const bool okz = ((unsigned)z < DSZ);
        const int zc = min(max(z, 0), DSZ - 1);
        #pragma unroll
        for (int kh = 0; kh < 3; kh++) {
            const int y = h + kh - 1;
            const bool okzy = okz && ((unsigned)y < DSZ);
            const int yc = min(max(y, 0), DSZ - 1);
            const int rowb = ((zc << 7) + yc) << 7;
            #pragma unroll
            for (int kw = 0; kw < 3; kw++) {
                const int xx = w + kw - 1;
                const bool ok = okzy && ((unsigned)xx < DSZ);
                const int xc = min(max(xx, 0), DSZ - 1);
                const int tap = kd * 9 + kh * 3 + kw;
                _Float16 wt = (tap < 8) ? wa[tap] : (tap < 16) ? wbv[tap - 8]
                            : (tap < 24) ? wc[tap - 16] : wd[tap - 24];
                const float wf = ok ? (float)wt : 0.0f;
                acc = fmaf((float)in[rowb + xc], wf, acc);
            }
        }
    }

    if (TANH) outf[idx] = tanhf(acc);
    else      outh[idx] = (_Float16)acc;
}

// ---------------------------------------------------------------------------
// ws layout (~208 MiB): P0, P1 = padded interleaved slots (32.5 MiB each),
// WB interleaved [vox][32] (128 MiB), F1/G1/F2 planar fp16 (4 MiB each).
// ---------------------------------------------------------------------------
extern "C" void kernel_launch(void* const* d_in, const int* in_sizes, int n_in,
                              void* d_out, int out_size, void* d_ws, size_t ws_size,
                              hipStream_t stream)
{
    const float* x      = (const float*)d_in[0];
    const float* ac1_w1 = (const float*)d_in[1];
    const float* ac1_b1 = (const float*)d_in[2];
    const float* ac1_w2 = (const float*)d_in[3];
    const float* ac2_w1 = (const float*)d_in[4];
    const float* ac2_b1 = (const float*)d_in[5];
    const float* ac2_w2 = (const float*)d_in[6];
    const float* ac3_w1 = (const float*)d_in[7];
    const float* ac3_b1 = (const float*)d_in[8];
    const float* ac3_w2 = (const float*)d_in[9];
    const float* mid_w  = (const float*)d_in[10];
    const float* mid_b  = (const float*)d_in[11];
    const float* out_w  = (const float*)d_in[12];
    const float* out_b  = (const float*)d_in[13];
    float* out = (float*)d_out;

    char* ws = (char*)d_ws;
    const size_t PB  = (size_t)16384 * PROW * 8 * 2;     // 34,078,720 B
    const size_t WBB = (size_t)VOX * 32 * 2;             // 128 MiB
    const size_t MB  = 1024 * 1024;
    _Float16* P0 = (_Float16*)(ws);
    _Float16* P1 = (_Float16*)(ws + PB);
    _Float16* WB = (_Float16*)(ws + 2 * PB);
    _Float16* F1 = (_Float16*)(ws + 2 * PB + WBB);
    _Float16* G1 = (_Float16*)(ws + 2 * PB + WBB + 4 * MB);
    _Float16* F2 = (_Float16*)(ws + 2 * PB + WBB + 8 * MB);

    const dim3 blk(256);
    const dim3 gridT(VOX / 256);   // cast, aconv: 8192 blocks
    const dim3 gridM(VOX / 128);   // mfma kernels: 16384 blocks
    const dim3 gridP(64);          // zero_pad

    zero_pad<<<gridP, blk, 0, stream>>>(P0);
    zero_pad<<<gridP, blk, 0, stream>>>(P1);

    // ---- block 1 ----
    cast_hp<<<gridT, blk, 0, stream>>>(x, P0);                       // X16 = P0
    conv8x8_mfma<true ><<<gridM, blk, 0, stream>>>(P0, ac1_w1, ac1_b1, P1);  // H1
    conv8x27n_mfma<<<gridM, blk, 0, stream>>>(P1, ac1_w2, WB);
    aconv8i<<<gridT, blk, 0, stream>>>(P0, WB, P1);                  // (H1 dead)
    aconv8i<<<gridT, blk, 0, stream>>>(P1, WB, P0);                  // (X16 dead)
    aconv8i<<<gridT, blk, 0, stream>>>(P0, WB, P1);                  // C1 = P1
    // ---- mid conv ----
    conv8x8_mfma<false><<<gridM, blk, 0, stream>>>(P1, mid_w, mid_b, P0);    // M = P0
    // ---- block 2 ----
    conv8x8_mfma<true ><<<gridM, blk, 0, stream>>>(P0, ac2_w1, ac2_b1, P1);  // H2 (C1 dead)
    conv8x27n_mfma<<<gridM, blk, 0, stream>>>(P1, ac2_w2, WB);
    aconv8i<<<gridT, blk, 0, stream>>>(P0, WB, P1);                  // (H2 dead)
    aconv8i<<<gridT, blk, 0, stream>>>(P1, WB, P0);                  // (M dead)
    aconv8i<<<gridT, blk, 0, stream>>>(P0, WB, P1);                  // mid2 = P1
    // ---- block 3 (weights from mid2 = P1) ----
    conv8x8_mfma<true ><<<gridM, blk, 0, stream>>>(P1, ac3_w1, ac3_b1, P0);  // H3
    conv8x27n_mfma<<<gridM, blk, 0, stream>>>(P0, ac3_w2, WB);
    conv8x1_mfma<<<gridM, blk, 0, stream>>>(P1, out_w, out_b, F1);
    aconv1h<false><<<gridT, blk, 0, stream>>>(F1, WB, G1, nullptr);
    aconv1h<false><<<gridT, blk, 0, stream>>>(G1, WB, F2, nullptr);
    aconv1h<true ><<<gridT, blk, 0, stream>>>(F2, WB, nullptr, out);
}

// Round 11
// 819.710 us; speedup vs baseline: 5.5084x; 1.1725x over previous
//
#include <hip/hip_runtime.h>
#include <math.h>

#define DSZ 128
#define VOX (DSZ*DSZ*DSZ)  // 2,097,152 voxels
#define PD  130            // padded dim (halo 1 on all 6 faces)

typedef _Float16 half8 __attribute__((ext_vector_type(8)));
typedef _Float16 half4 __attribute__((ext_vector_type(4)));
typedef _Float16 half2v __attribute__((ext_vector_type(2)));
typedef float float4v __attribute__((ext_vector_type(4)));

// Halo-padded tensors: slot(z,y,x) = ((z+1)*130 + (y+1))*130 + (x+1),
// z,y,x in [-1,128]. 8-ch interleaved: halves = slot*8 (33.5 MiB).
// 1-ch: halves = slot (4.2 MiB). Halos zeroed once; interior-only writes.
// WB: interleaved [vox][32] halves (27 taps + 5 pad), 128 MiB.

// ---------------------------------------------------------------------------
// Zero the halo of a padded tensor (ws is re-poisoned before every call).
// ---------------------------------------------------------------------------
template<int CH>
__global__ __launch_bounds__(256) void zero_halo(_Float16* __restrict__ P)
{
    const int t = blockIdx.x * 256 + threadIdx.x;   // (zp,yp) row in [0,130)^2
    if (t >= PD * PD) return;
    const int zp = t / PD;
    const int yp = t - zp * PD;
    _Float16* row = P + (size_t)t * PD * CH;
    if (zp == 0 || zp == PD - 1 || yp == 0 || yp == PD - 1) {
        if (CH == 8) {
            half8 zz = {};
            for (int x = 0; x < PD; ++x) *(half8*)&row[x * 8] = zz;
        } else {
            for (int x = 0; x < PD; ++x) row[x] = (_Float16)0.0f;
        }
    } else {
        if (CH == 8) {
            half8 zz = {};
            *(half8*)&row[0] = zz;
            *(half8*)&row[(PD - 1) * 8] = zz;
        } else {
            row[0] = (_Float16)0.0f;
            row[PD - 1] = (_Float16)0.0f;
        }
    }
}

// ---------------------------------------------------------------------------
// Preformat conv weights -> fp16 [oc][tap(stride 29)][ic], once per launch.
// Blocks: 0..2 = ac{1,2,3}_w1; 3 = out_w; 4 = mid_w; 5..7 = ac{1,2,3}_w2.
// ---------------------------------------------------------------------------
__global__ __launch_bounds__(256) void preformat(const float* __restrict__ w1a, const float* __restrict__ w1b,
                                                 const float* __restrict__ w1c, const float* __restrict__ outw,
                                                 const float* __restrict__ midw,
                                                 const float* __restrict__ w2a, const float* __restrict__ w2b,
                                                 const float* __restrict__ w2c, _Float16* __restrict__ WF)
{
    const int bid = blockIdx.x, tid = threadIdx.x;
    const float* src;
    _Float16* dst;
    int nelem, sz;
    if (bid < 3)       { src = bid == 0 ? w1a : bid == 1 ? w1b : w1c; dst = WF + bid * 3712; nelem = 8 * 216; sz = 16 * 29; }
    else if (bid == 3) { src = outw; dst = WF + 3 * 3712; nelem = 216;     sz = 16 * 29; }
    else if (bid == 4) { src = midw; dst = WF + 4 * 3712; nelem = 8 * 216; sz = 16 * 29; }
    else               { src = bid == 5 ? w2a : bid == 6 ? w2b : w2c; dst = WF + 5 * 3712 + (bid - 5) * 7424; nelem = 27 * 216; sz = 32 * 29; }
    for (int i = tid; i < sz; i += 256) ((half8*)dst)[i] = half8{};
    __syncthreads();
    for (int i = tid; i < nelem; i += 256) {
        const int oc = i / 216;
        const int rem = i - oc * 216;
        const int ic = rem / 27;
        const int tap = rem - ic * 27;
        dst[(oc * 29 + tap) * 8 + ic] = (_Float16)src[i];
    }
}

// ---------------------------------------------------------------------------
// Cast planar fp32 (8ch) -> halo-padded interleaved fp16 (interior only).
// ---------------------------------------------------------------------------
__global__ __launch_bounds__(256) void cast_hp(const float* __restrict__ in,
                                               _Float16* __restrict__ hp)
{
    const int idx = blockIdx.x * 256 + threadIdx.x;
    const int w = idx & 127;
    const int h = (idx >> 7) & 127;
    const int d = idx >> 14;
    half8 v;
    #pragma unroll
    for (int ic = 0; ic < 8; ++ic) v[ic] = (_Float16)in[(size_t)ic * VOX + idx];
    const int slot = ((d + 1) * PD + (h + 1)) * PD + (w + 1);
    *(half8*)&hp[(size_t)slot * 8] = v;
}

// ---------------------------------------------------------------------------
// Dense 3x3x3 conv 8->8 (+bias, opt relu) via MFMA; padded in/out, ROWS=2.
// ---------------------------------------------------------------------------
template<bool RELU>
__global__ __launch_bounds__(256) void conv8x8_mfma(const _Float16* __restrict__ DP,
                                                    const _Float16* __restrict__ WF,
                                                    const float* __restrict__ bias,
                                                    _Float16* __restrict__ HO)
{
    __shared__ _Float16 Wr[16 * 29 * 8];
    const int tid = threadIdx.x;
    for (int i = tid; i < 16 * 29; i += 256) ((half8*)Wr)[i] = ((const half8*)WF)[i];
    __syncthreads();

    const int b = ((blockIdx.x & 7) << 10) | (blockIdx.x >> 3);  // 8192 blocks
    const int h0 = (b & 63) << 1;
    const int d  = b >> 6;
    const int lane = tid & 63;
    const int wv   = tid >> 6;
    const int col  = lane & 15;
    const int q    = lane >> 4;

    half8 af[7];
    #pragma unroll
    for (int c = 0; c < 7; ++c)
        af[c] = *(const half8*)&Wr[(col * 29 + (c * 4 + q)) * 8];

    const int base0 = ((d + 1) * PD + (h0 + 1)) * PD + 1 + wv * 32 + col;
    const _Float16* p[7];
    #pragma unroll
    for (int c = 0; c < 7; ++c) {
        const int tap = min(c * 4 + q, 26);
        const int dz = tap / 9, r9 = tap - dz * 9;
        const int dy = r9 / 3,  dx = r9 - dy * 3;
        p[c] = DP + (size_t)(base0 + ((dz - 1) * PD + (dy - 1)) * PD + (dx - 1)) * 8;
    }

    #pragma unroll
    for (int r = 0; r < 2; ++r) {
        #pragma unroll
        for (int t2 = 0; t2 < 2; ++t2) {
            float4v acc = {0.0f, 0.0f, 0.0f, 0.0f};
            #pragma unroll
            for (int c = 0; c < 7; ++c) {
                const half8 bv = *(const half8*)(p[c] + (r * PD + t2 * 16) * 8);
                acc = __builtin_amdgcn_mfma_f32_16x16x32_f16(af[c], bv, acc, 0, 0, 0);
            }
            if (q < 2) {
                const float4v bl = ((const float4v*)bias)[q];
                half4 hv;
                #pragma unroll
                for (int rr = 0; rr < 4; ++rr) {
                    float v = acc[rr] + bl[rr];
                    if (RELU) v = fmaxf(v, 0.0f);
                    hv[rr] = (_Float16)v;
                }
                *(half4*)&HO[(size_t)(base0 + r * PD + t2 * 16) * 8 + q * 4] = hv;
            }
        }
    }
}

// ---------------------------------------------------------------------------
// Dense 3x3x3 conv 8->1 (+bias) via MFMA; padded in -> padded 1-ch fp16 out.
// ---------------------------------------------------------------------------
__global__ __launch_bounds__(256) void conv8x1_mfma(const _Float16* __restrict__ DP,
                                                    const _Float16* __restrict__ WF,
                                                    const float* __restrict__ bias,
                                                    _Float16* __restrict__ F)
{
    __shared__ _Float16 Wr[16 * 29 * 8];
    const int tid = threadIdx.x;
    for (int i = tid; i < 16 * 29; i += 256) ((half8*)Wr)[i] = ((const half8*)WF)[i];
    __syncthreads();

    const int b = ((blockIdx.x & 7) << 10) | (blockIdx.x >> 3);
    const int h0 = (b & 63) << 1;
    const int d  = b >> 6;
    const int lane = tid & 63;
    const int wv   = tid >> 6;
    const int col  = lane & 15;
    const int q    = lane >> 4;

    half8 af[7];
    #pragma unroll
    for (int c = 0; c < 7; ++c)
        af[c] = *(const half8*)&Wr[(col * 29 + (c * 4 + q)) * 8];

    const int base0 = ((d + 1) * PD + (h0 + 1)) * PD + 1 + wv * 32 + col;
    const _Float16* p[7];
    #pragma unroll
    for (int c = 0; c < 7; ++c) {
        const int tap = min(c * 4 + q, 26);
        const int dz = tap / 9, r9 = tap - dz * 9;
        const int dy = r9 / 3,  dx = r9 - dy * 3;
        p[c] = DP + (size_t)(base0 + ((dz - 1) * PD + (dy - 1)) * PD + (dx - 1)) * 8;
    }

    const float b0 = bias[0];
    #pragma unroll
    for (int r = 0; r < 2; ++r) {
        #pragma unroll
        for (int t2 = 0; t2 < 2; ++t2) {
            float4v acc = {0.0f, 0.0f, 0.0f, 0.0f};
            #pragma unroll
            for (int c = 0; c < 7; ++c) {
                const half8 bv = *(const half8*)(p[c] + (r * PD + t2 * 16) * 8);
                acc = __builtin_amdgcn_mfma_f32_16x16x32_f16(af[c], bv, acc, 0, 0, 0);
            }
            if (q == 0)
                F[base0 + r * PD + t2 * 16] = (_Float16)(acc[0] + b0);
        }
    }
}

// ---------------------------------------------------------------------------
// 8 -> 27 conv + L1 normalize via MFMA; padded in, WB out [vox][32]. ROWS=2.
// ---------------------------------------------------------------------------
__global__ __launch_bounds__(256) void conv8x27n_mfma(const _Float16* __restrict__ HP,
                                                      const _Float16* __restrict__ WF,
                                                      _Float16* __restrict__ WB)
{
    __shared__ _Float16 Wr[32 * 29 * 8];
    const int tid = threadIdx.x;
    for (int i = tid; i < 32 * 29; i += 256) ((half8*)Wr)[i] = ((const half8*)WF)[i];
    __syncthreads();

    const int b = ((blockIdx.x & 7) << 10) | (blockIdx.x >> 3);  // 8192 blocks
    const int h0 = (b & 63) << 1;
    const int d  = b >> 6;
    const int lane = tid & 63;
    const int wv   = tid >> 6;
    const int col  = lane & 15;
    const int q    = lane >> 4;

    half8 af[2][7];
    #pragma unroll
    for (int t = 0; t < 2; ++t)
        #pragma unroll
        for (int c = 0; c < 7; ++c)
            af[t][c] = *(const half8*)&Wr[((t * 16 + col) * 29 + (c * 4 + q)) * 8];

    const int base0 = ((d + 1) * PD + (h0 + 1)) * PD + 1 + wv * 32 + col;
    const _Float16* p[7];
    #pragma unroll
    for (int c = 0; c < 7; ++c) {
        const int tap = min(c * 4 + q, 26);
        const int dz = tap / 9, r9 = tap - dz * 9;
        const int dy = r9 / 3,  dx = r9 - dy * 3;
        p[c] = HP + (size_t)(base0 + ((dz - 1) * PD + (dy - 1)) * PD + (dx - 1)) * 8;
    }

    #pragma unroll
    for (int r = 0; r < 2; ++r) {
        #pragma unroll
        for (int t2 = 0; t2 < 2; ++t2) {
            float4v acc0 = {0.0f, 0.0f, 0.0f, 0.0f};
            float4v acc1 = {0.0f, 0.0f, 0.0f, 0.0f};
            #pragma unroll
            for (int c = 0; c < 7; ++c) {
                const half8 bv = *(const half8*)(p[c] + (r * PD + t2 * 16) * 8);
                acc0 = __builtin_amdgcn_mfma_f32_16x16x32_f16(af[0][c], bv, acc0, 0, 0, 0);
                acc1 = __builtin_amdgcn_mfma_f32_16x16x32_f16(af[1][c], bv, acc1, 0, 0, 0);
            }

            float s = 0.0f;
            #pragma unroll
            for (int rr = 0; rr < 4; ++rr) {
                s += fabsf(acc0[rr]);
                if (16 + q * 4 + rr < 27) s += fabsf(acc1[rr]);
            }
            s += __shfl_xor(s, 16);
            s += __shfl_xor(s, 32);
            const float rcp = 1.0f / fmaxf(s, 1e-12f);

            const int vox = (d << 14) + ((h0 + r) << 7) + wv * 32 + t2 * 16 + col;
            const size_t base = (size_t)vox * 32;
            half4 o0, o1;
            #pragma unroll
            for (int rr = 0; rr < 4; ++rr) {
                o0[rr] = (_Float16)(acc0[rr] * rcp);
                o1[rr] = (_Float16)(acc1[rr] * rcp);   // pad rows write 0
            }
            *(half4*)&WB[base + q * 4]      = o0;
            *(half4*)&WB[base + 16 + q * 4] = o1;
        }
    }
}

// ---------------------------------------------------------------------------
// Adaptive stencil, 8ch padded interleaved in/out; no boundary logic.
// ---------------------------------------------------------------------------
__global__ __launch_bounds__(256) void aconv8i(const _Float16* __restrict__ in,
                                               const _Float16* __restrict__ wb,
                                               _Float16* __restrict__ out)
{
    const int b = ((blockIdx.x & 7) << 10) | (blockIdx.x >> 3);  // 8192 blocks
    const int idx = b * 256 + threadIdx.x;
    const int w = idx & 127;
    const int h = (idx >> 7) & 127;
    const int d = idx >> 14;

    const size_t wbb = (size_t)idx * 32;
    const half8 wA = *(const half8*)(wb + wbb);
    const half8 wB = *(const half8*)(wb + wbb + 8);
    const half8 wC = *(const half8*)(wb + wbb + 16);
    const half8 wD = *(const half8*)(wb + wbb + 24);

    const int s0 = ((d + 1) * PD + (h + 1)) * PD + (w + 1);

    half2v a4[4];
    #pragma unroll
    for (int j = 0; j < 4; ++j) a4[j] = half2v{};

    #pragma unroll
    for (int dz = 0; dz < 3; dz++) {
        #pragma unroll
        for (int dy = 0; dy < 3; dy++) {
            const _Float16* rp = in + (size_t)(s0 + ((dz - 1) * PD + (dy - 1)) * PD) * 8;
            #pragma unroll
            for (int kw = 0; kw < 3; kw++) {
                const int tap = dz * 9 + dy * 3 + kw;
                const _Float16 wt = (tap < 8) ? wA[tap] : (tap < 16) ? wB[tap - 8]
                                 : (tap < 24) ? wC[tap - 16] : wD[tap - 24];
                half2v w2; w2[0] = wt; w2[1] = wt;
                const half8 hv = *(const half8*)(rp + (kw - 1) * 8);
                const half2v* h2 = (const half2v*)&hv;
                #pragma unroll
                for (int j = 0; j < 4; ++j)
                    a4[j] += h2[j] * w2;                 // v_pk_fma_f16
            }
        }
    }

    half8 o;
    #pragma unroll
    for (int j = 0; j < 4; ++j) { o[2 * j] = a4[j][0]; o[2 * j + 1] = a4[j][1]; }
    *(half8*)&out[(size_t)s0 * 8] = o;
}

// ---------------------------------------------------------------------------
// Adaptive stencil, 1ch padded fp16 in; fp32 math.
// TANH=false: padded fp16 out. TANH=true: planar fp32 out (final).
// ---------------------------------------------------------------------------
template<bool TANH>
__global__ __launch_bounds__(256) void aconv1h(const _Float16* __restrict__ in,
                                               const _Float16* __restrict__ wb,
                                               _Float16* __restrict__ outh,
                                               float* __restrict__ outf)
{
    const int b = ((blockIdx.x & 7) << 10) | (blockIdx.x >> 3);
    const int idx = b * 256 + threadIdx.x;
    const int w = idx & 127;
    const int h = (idx >> 7) & 127;
    const int d = idx >> 14;

    const size_t wbb = (size_t)idx * 32;
    const half8 wA = *(const half8*)(wb + wbb);
    const half8 wB = *(const half8*)(wb + wbb + 8);
    const half8 wC = *(const half8*)(wb + wbb + 16);
    const half8 wD = *(const half8*)(wb + wbb + 24);

    const int s0 = ((d + 1) * PD + (h + 1)) * PD + (w + 1);

    float acc = 0.0f;
    #pragma unroll
    for (int dz = 0; dz < 3; dz++) {
        #pragma unroll
        for (int dy = 0; dy < 3; dy++) {
            const _Float16* rp = in + s0 + ((dz - 1) * PD + (dy - 1)) * PD;
            #pragma unroll
            for (int kw = 0; kw < 3; kw++) {
                const int tap = dz * 9 + dy * 3 + kw;
                const _Float16 wt = (tap < 8) ? wA[tap] : (tap < 16) ? wB[tap - 8]
                                 : (tap < 24) ? wC[tap - 16] : wD[tap - 24];
                acc = fmaf((float)rp[kw - 1], (float)wt, acc);
            }
        }
    }

    if (TANH) outf[idx] = tanhf(acc);
    else      outh[s0] = (_Float16)acc;
}

// ---------------------------------------------------------------------------
// ws layout (~208 MiB): P0 | P1 (33.5 MiB padded 8-ch each) | WB (128 MiB)
//   | F1 | G1 | F2 (4.2 MiB padded 1-ch each) | WF (preformatted weights).
// WF halves: [0]=ac1_w1 [3712]=ac2_w1 [7424]=ac3_w1 [11136]=out_w
//   [14848]=mid_w [18560]=ac1_w2 [25984]=ac2_w2 [33408]=ac3_w2
// ---------------------------------------------------------------------------
extern "C" void kernel_launch(void* const* d_in, const int* in_sizes, int n_in,
                              void* d_out, int out_size, void* d_ws, size_t ws_size,
                              hipStream_t stream)
{
    const float* x      = (const float*)d_in[0];
    const float* ac1_w1 = (const float*)d_in[1];
    const float* ac1_b1 = (const float*)d_in[2];
    const float* ac1_w2 = (const float*)d_in[3];
    const float* ac2_w1 = (const float*)d_in[4];
    const float* ac2_b1 = (const float*)d_in[5];
    const float* ac2_w2 = (const float*)d_in[6];
    const float* ac3_w1 = (const float*)d_in[7];
    const float* ac3_b1 = (const float*)d_in[8];
    const float* ac3_w2 = (const float*)d_in[9];
    const float* mid_w  = (const float*)d_in[10];
    const float* mid_b  = (const float*)d_in[11];
    const float* out_w  = (const float*)d_in[12];
    const float* out_b  = (const float*)d_in[13];
    float* out = (float*)d_out;

    char* ws = (char*)d_ws;
    const size_t PS8 = (size_t)PD * PD * PD * 8 * 2;   // 35,152,000 B
    const size_t PS1 = (size_t)PD * PD * PD * 2;       //  4,394,000 B
    _Float16* P0 = (_Float16*)(ws);
    _Float16* P1 = (_Float16*)(ws + PS8);
    _Float16* WB = (_Float16*)(ws + 2 * PS8);
    _Float16* F1 = (_Float16*)(ws + 2 * PS8 + (size_t)134217728);
    _Float16* G1 = (_Float16*)(ws + 2 * PS8 + (size_t)134217728 + PS1);
    _Float16* F2 = (_Float16*)(ws + 2 * PS8 + (size_t)134217728 + 2 * PS1);
    _Float16* WF = (_Float16*)(ws + 2 * PS8 + (size_t)134217728 + 3 * PS1);
    _Float16* WF8_1  = WF;
    _Float16* WF8_2  = WF + 3712;
    _Float16* WF8_3  = WF + 7424;
    _Float16* WFo    = WF + 11136;
    _Float16* WFmid  = WF + 14848;
    _Float16* WF27_1 = WF + 18560;
    _Float16* WF27_2 = WF + 25984;
    _Float16* WF27_3 = WF + 33408;

    const dim3 blk(256);
    const dim3 gridT(VOX / 256);               // cast, aconv: 8192 blocks
    const dim3 gridM(VOX / 256);               // MFMA convs (ROWS=2): 8192 blocks
    const dim3 gridZ((PD * PD + 255) / 256);   // zero_halo: 67 blocks

    zero_halo<8><<<gridZ, blk, 0, stream>>>(P0);
    zero_halo<8><<<gridZ, blk, 0, stream>>>(P1);
    zero_halo<1><<<gridZ, blk, 0, stream>>>(F1);
    zero_halo<1><<<gridZ, blk, 0, stream>>>(G1);
    zero_halo<1><<<gridZ, blk, 0, stream>>>(F2);
    preformat<<<dim3(8), blk, 0, stream>>>(ac1_w1, ac2_w1, ac3_w1, out_w, mid_w,
                                           ac1_w2, ac2_w2, ac3_w2, WF);

    // ---- block 1 ----
    cast_hp<<<gridT, blk, 0, stream>>>(x, P0);                       // X16 = P0
    conv8x8_mfma<true ><<<gridM, blk, 0, stream>>>(P0, WF8_1, ac1_b1, P1);   // H1
    conv8x27n_mfma<<<gridM, blk, 0, stream>>>(P1, WF27_1, WB);
    aconv8i<<<gridT, blk, 0, stream>>>(P0, WB, P1);                  // (H1 dead)
    aconv8i<<<gridT, blk, 0, stream>>>(P1, WB, P0);
    aconv8i<<<gridT, blk, 0, stream>>>(P0, WB, P1);                  // C1 = P1
    // ---- mid conv ----
    conv8x8_mfma<false><<<gridM, blk, 0, stream>>>(P1, WFmid, mid_b, P0);    // M = P0
    // ---- block 2 ----
    conv8x8_mfma<true ><<<gridM, blk, 0, stream>>>(P0, WF8_2, ac2_b1, P1);   // H2
    conv8x27n_mfma<<<gridM, blk, 0, stream>>>(P1, WF27_2, WB);
    aconv8i<<<gridT, blk, 0, stream>>>(P0, WB, P1);
    aconv8i<<<gridT, blk, 0, stream>>>(P1, WB, P0);
    aconv8i<<<gridT, blk, 0, stream>>>(P0, WB, P1);                  // mid2 = P1
    // ---- block 3 (weights from mid2 = P1) ----
    conv8x8_mfma<true ><<<gridM, blk, 0, stream>>>(P1, WF8_3, ac3_b1, P0);   // H3
    conv8x27n_mfma<<<gridM, blk, 0, stream>>>(P0, WF27_3, WB);
    conv8x1_mfma<<<gridM, blk, 0, stream>>>(P1, WFo, out_b, F1);
    aconv1h<false><<<gridT, blk, 0, stream>>>(F1, WB, G1, nullptr);
    aconv1h<false><<<gridT, blk, 0, stream>>>(G1, WB, F2, nullptr);
    aconv1h<true ><<<gridT, blk, 0, stream>>>(F2, WB, nullptr, out);
}